// Round 6
// baseline (958.958 us; speedup 1.0000x reference)
//
#include <hip/hip_runtime.h>
#include <hip/hip_fp16.h>

#define DI __device__ __forceinline__

constexpr int NGRAPH = 500;
constexpr int EDGES  = 800000;

// ---- workspace layout (4-byte units) ----
constexpr size_t WI_HIST = 0;                    // [500]
constexpr size_t WI_OFF  = 512;                  // [501]
constexpr size_t WI_CURS = 1024;                 // [500]
constexpr size_t WI_META = 1536;                 // [E]
constexpr size_t WI_ORIG = WI_META + EDGES;      // [E]
constexpr size_t WF_PREP = WI_ORIG + EDGES;      // 656 floats (16B aligned)
constexpr size_t WF_WFRAG = WF_PREP + 672;       // uint4[5120]: W-frags[4096] + We-frags[1024]

// ---- LDS layout (bytes), total 65072 (2 blocks/CU) ----
constexpr int S_H   = 0;       // f16 h[100][40]   (cols 0..31 used)
constexpr int S_HP  = 8000;    // f16 hp[100][128] (col c -> d=c>>2, h=c&3), XOR-swizzled
constexpr int S_U   = 33600;   // f16 U[100][132]  (4 rels x 32 dims + pad)
constexpr int S_EH  = 60000;   // f32[100][4]
constexpr int S_ET  = 61600;   // f32[100][4]
constexpr int S_DEN = 63200;   // f32[100][4]
constexpr int S_RA  = 64800;   // f32[16][4]
constexpr int S_ESG = 65056;   // f32[4]
constexpr int S_TOTAL = 65072;

typedef _Float16 f16x8 __attribute__((ext_vector_type(8)));
typedef float f32x4 __attribute__((ext_vector_type(4)));

DI float lrelu(float x) { return x >= 0.f ? x : 0.2f * x; }
DI f16x8 u4_to_f16x8(uint4 u) { f16x8 r; __builtin_memcpy(&r, &u, 16); return r; }
DI f16x8 two_u2(uint2 a, uint2 b) { return u4_to_f16x8(make_uint4(a.x, a.y, b.x, b.y)); }

// hp swizzle: half-index for (node n, col c); XOR bits 3..5 with n&7 (16B granularity)
DI int hpIdx(int n, int c) { return n * 128 + (c ^ ((n & 7) << 3)); }

// packed f16 LDS atomic add (ds_pk_add_f16); generic LDS ptr low 32 bits = LDS offset
DI void ldsPkAddF16(__half* p, float v0, float v1) {
    __half2 hv = __floats2half2_rn(v0, v1);
    unsigned uv; __builtin_memcpy(&uv, &hv, 4);
    unsigned addr = (unsigned)(unsigned long long)p;
    asm volatile("ds_pk_add_f16 %0, %1" :: "v"(addr), "v"(uv) : "memory");
}

// ---------------- binning (graph-only bins) ----------------
__global__ void k_zero(int* hist) {
    int i = threadIdx.x;
    if (i < NGRAPH) hist[i] = 0;
}

__global__ void k_hist(const int* __restrict__ dst, int* __restrict__ hist) {
    int e = blockIdx.x * 1024 + threadIdx.x;
    if (e < EDGES) atomicAdd(&hist[(unsigned)dst[e] / 100u], 1);
}

__global__ void k_scan(const int* __restrict__ hist, int* __restrict__ off,
                       int* __restrict__ curs) {
    __shared__ int sc[512];
    int t = threadIdx.x;
    int v = (t < NGRAPH) ? hist[t] : 0;
    sc[t] = v;
    __syncthreads();
    for (int o = 1; o < 512; o <<= 1) {
        int a = (t >= o) ? sc[t - o] : 0;
        __syncthreads();
        sc[t] += a;
        __syncthreads();
    }
    int excl = sc[t] - v;
    if (t < NGRAPH) { off[t] = excl; curs[t] = excl; }
    if (t == 0) off[NGRAPH] = EDGES;
}

__global__ void k_scatter(const int* __restrict__ src, const int* __restrict__ dst,
                          const int* __restrict__ rt, int* __restrict__ curs,
                          int* __restrict__ meta, int* __restrict__ orig) {
    int e = blockIdx.x * 256 + threadIdx.x;
    if (e >= EDGES) return;
    int s = src[e], d = dst[e], r = rt[e];
    int g = (unsigned)d / 100u;
    int pos = atomicAdd(&curs[g], 1);
    meta[pos] = (s - g * 100) | ((d - g * 100) << 7) | (r << 14);
    orig[pos] = e;
}

// ---------------- setup: prep folds + f16 MFMA fragments ----------------
__global__ void k_setup(const float* __restrict__ rel_table, const float* __restrict__ Wr,
                        const float* __restrict__ br, const float* __restrict__ We,
                        const float* __restrict__ be, const float* __restrict__ attn_r,
                        const float* __restrict__ attn_rs, const float* __restrict__ attn_s,
                        const float* __restrict__ W, float* __restrict__ prep,
                        uint4* __restrict__ wf) {
    __shared__ float wra[2][32][4];
    __shared__ float sbias[2][3][4];
    int b = blockIdx.x, t = threadIdx.x;
    if (b == 0) {
        // prep: er[2][16][4]@0, wrs[2][32][4]@128, wes[2][32][4]@384, bias_es@640, bias_esg@648
        {
            int l = t >> 7, k = (t >> 2) & 31, h = t & 3;
            float a = 0.f, bb = 0.f, c = 0.f;
            for (int d2 = 0; d2 < 32; ++d2) {
                float w1 = Wr[(size_t)(l*32 + k)*128 + h*32 + d2];
                float w2 = We[(size_t)(l*32 + k)*128 + h*32 + d2];
                a  += w1 * attn_r [l*128 + h*32 + d2];
                bb += w1 * attn_rs[l*128 + h*32 + d2];
                c  += w2 * attn_s [l*128 + h*32 + d2];
            }
            wra[l][k][h] = a;
            prep[128 + (l*32 + k)*4 + h] = bb;
            prep[384 + (l*32 + k)*4 + h] = c;
        }
        if (t < 24) {
            int l = t / 12, which = (t % 12) / 4, h = t % 4;
            const float* bp = (which == 2) ? be : br;
            const float* ap = (which == 0) ? attn_r : (which == 1 ? attn_rs : attn_s);
            float s = 0.f;
            for (int d2 = 0; d2 < 32; ++d2) s += bp[l*128 + h*32 + d2] * ap[l*128 + h*32 + d2];
            sbias[l][which][h] = s;
        }
        __syncthreads();
        if (t < 128) {
            int l = t >> 6, r = (t >> 2) & 15, h = t & 3;
            float s = sbias[l][0][h];
            for (int k = 0; k < 32; ++k) s += rel_table[r*32 + k] * wra[l][k][h];
            prep[(l*16 + r)*4 + h] = s;
        }
        if (t < 8) {
            int l = t >> 2, h = t & 3;
            prep[640 + l*4 + h] = sbias[l][1][h];
            prep[648 + l*4 + h] = sbias[l][2][h];
        }
    } else if (b <= 16) {
        // W fragments (f16): wf[((l*16+rel)*2+Nt)*64 + ln]
        int fi = (b - 1) * 256 + t;  // 0..4095
        int ln = fi & 63, Nt = (fi >> 6) & 1, rel = (fi >> 7) & 15, l = fi >> 11;
        int j = Nt*16 + (ln & 15), k0 = (ln >> 4) << 3;
        unsigned short fr[8];
        #pragma unroll
        for (int i = 0; i < 8; ++i) {
            __half hv = __float2half(W[(((size_t)l*16 + rel)*32 + k0 + i)*32 + j]);
            __builtin_memcpy(&fr[i], &hv, 2);
        }
        uint4 o;
        o.x = fr[0] | ((unsigned)fr[1] << 16);
        o.y = fr[2] | ((unsigned)fr[3] << 16);
        o.z = fr[4] | ((unsigned)fr[5] << 16);
        o.w = fr[6] | ((unsigned)fr[7] << 16);
        wf[fi] = o;
    } else {
        // We fragments (f16, column-permuted): wfe[(l*8+Nt)*64 + ln], col c -> phys (c&3)*32+(c>>2)
        int fi = (b - 17) * 256 + t;  // 0..1023
        int ln = fi & 63, Nt = (fi >> 6) & 7, l = fi >> 9;
        int c = Nt*16 + (ln & 15);
        int phys = (c & 3)*32 + (c >> 2);
        int k0 = (ln >> 4) << 3;
        unsigned short fr[8];
        #pragma unroll
        for (int i = 0; i < 8; ++i) {
            __half hv = __float2half(We[(size_t)l*4096 + (k0 + i)*128 + phys]);
            __builtin_memcpy(&fr[i], &hv, 2);
        }
        uint4 o;
        o.x = fr[0] | ((unsigned)fr[1] << 16);
        o.y = fr[2] | ((unsigned)fr[3] << 16);
        o.z = fr[4] | ((unsigned)fr[5] << 16);
        o.w = fr[6] | ((unsigned)fr[7] << 16);
        wf[4096 + fi] = o;
    }
}

// ---------------- fused per-graph forward ----------------
__global__ void __launch_bounds__(512, 4)
k_fused(const float* __restrict__ state, const float* __restrict__ rw,
        const float* __restrict__ code_emb, const float* __restrict__ h_bias,
        const float* __restrict__ be, const float* __restrict__ attn_h,
        const float* __restrict__ attn_t, const int* __restrict__ node_ids,
        const int* __restrict__ off, const int* __restrict__ meta,
        const int* __restrict__ orig, const float* __restrict__ prep,
        const uint4* __restrict__ wf,
        float* __restrict__ xout, float* __restrict__ relOut, float* __restrict__ edgeOut) {
    extern __shared__ char smem[];
    __half* hH  = (__half*)(smem + S_H);
    __half* hpH = (__half*)(smem + S_HP);
    __half* Uh  = (__half*)(smem + S_U);
    float* ehp  = (float*)(smem + S_EH);
    float* etp  = (float*)(smem + S_ET);
    float* denp = (float*)(smem + S_DEN);
    float* rap  = (float*)(smem + S_RA);
    float* esgp = (float*)(smem + S_ESG);
    const uint4* wfe = wf + 4096;

    const int g = blockIdx.x;
    const int t = threadIdx.x;
    const int lane = t & 63, w = t >> 6;
    const int ln15 = lane & 15, q = lane >> 4, q8 = q << 3;
    const int MtA = w % 7, NtA = w / 7;
    const int MtB = (w + 8) % 7, NtB = (w + 8) / 7;
    const bool hasB = (w < 6);
    const int colc = w * 16 + ln15;                 // hp column this lane owns in P2
    const int physc = (colc & 3) * 32 + (colc >> 2);

    const int gbase = off[g];
    const int ecnt  = off[g + 1] - gbase;

    // P0: h0 = code_emb[node_ids] (f16, [100][40]); zero eh/et/den
    for (int i = t; i < 1600; i += 512) {
        int n = i >> 4, dp = i & 15;
        int id = node_ids[g * 100 + n];
        float2 v = *(const float2*)&code_emb[(size_t)id * 32 + dp * 2];
        *(__half2*)&hH[n * 40 + dp * 2] = __floats2half2_rn(v.x, v.y);
    }
    for (int i = t; i < 300; i += 512) ((uint4*)(smem + S_EH))[i] = make_uint4(0, 0, 0, 0);

    // edges -> registers (4 slots per thread)
    int em[4];
    #pragma unroll
    for (int k = 0; k < 4; ++k) {
        int e = t + k * 512;
        em[k] = (e < ecnt) ? meta[gbase + e] : -1;
    }
    float cc[4][4];

    auto scatterPass = [&](int p) {
        #pragma unroll
        for (int k = 0; k < 4; ++k) {
            int m = em[k];
            if (m >= 0 && ((m >> 16) & 3) == p) {
                int s = m & 127, d = (m >> 7) & 127;
                int cb = ((m >> 14) & 3) * 32;
                int sw = (s & 7) << 3;
                float c0 = cc[k][0], c1 = cc[k][1], c2 = cc[k][2], c3 = cc[k][3];
                #pragma unroll
                for (int db = 0; db < 16; ++db) {
                    // logical cols [db*8, db*8+8) = dims {2db, 2db+1} x 4 heads
                    uint4 hv = *(const uint4*)&hpH[s * 128 + ((db * 8) ^ sw)];
                    float2 f01 = __half22float2(*(const __half2*)&hv.x);
                    float2 f23 = __half22float2(*(const __half2*)&hv.y);
                    float2 f45 = __half22float2(*(const __half2*)&hv.z);
                    float2 f67 = __half22float2(*(const __half2*)&hv.w);
                    float v0 = c0*f01.x + c1*f01.y + c2*f23.x + c3*f23.y;
                    float v1 = c0*f45.x + c1*f45.y + c2*f67.x + c3*f67.y;
                    ldsPkAddF16(Uh + d * 132 + cb + db * 2, v0, v1);
                }
            }
        }
    };

    for (int l = 0; l < 2; ++l) {
        __syncthreads();   // B0: h ready, eh/et/den zeroed

        // ---- X1: P2-MFMA (hp = h@We + be) + eh/et epilogue + P1 rel-att ----
        {
            uint4 bwe = wfe[(l * 8 + w) * 64 + lane];
            f16x8 bw = u4_to_f16x8(bwe);
            f32x4 pacc[7];
            #pragma unroll
            for (int Mt = 0; Mt < 7; ++Mt) {
                const __half* hr = hH + (Mt * 16 + ln15) * 40 + q8;
                f16x8 af = two_u2(*(const uint2*)hr, *(const uint2*)(hr + 4));
                f32x4 z = {0.f, 0.f, 0.f, 0.f};
                pacc[Mt] = __builtin_amdgcn_mfma_f32_16x16x32_f16(af, bw, z, 0, 0, 0);
            }
            float beC = be[l * 128 + physc];
            float ahC = attn_h[l * 128 + physc];
            float atC = attn_t[l * 128 + physc];
            #pragma unroll
            for (int Mt = 0; Mt < 7; ++Mt) {
                #pragma unroll
                for (int i = 0; i < 4; ++i) {
                    int n = Mt * 16 + q * 4 + i;
                    float hv = pacc[Mt][i] + beC;
                    bool ok = (n < 100);
                    if (ok) hpH[hpIdx(n, colc)] = __float2half(hv);
                    float veh = ok ? hv * ahC : 0.f;
                    float vet = ok ? hv * atC : 0.f;
                    veh += __shfl_xor(veh, 4); vet += __shfl_xor(vet, 4);
                    veh += __shfl_xor(veh, 8); vet += __shfl_xor(vet, 8);
                    if (ok && (ln15 & 12) == 0) {
                        atomicAdd(&ehp[n * 4 + (ln15 & 3)], veh);
                        atomicAdd(&etp[n * 4 + (ln15 & 3)], vet);
                    }
                }
            }
        }
        {   // P1: relation attention (all waves redundantly)
            int k32 = lane & 31;
            float sG = state[g * 32 + k32];
            float4 frs = *(const float4*)&prep[128 + l * 128 + k32 * 4];
            float4 fes = *(const float4*)&prep[384 + l * 128 + k32 * 4];
            float p0 = sG * frs.x, p1 = sG * frs.y, p2 = sG * frs.z, p3 = sG * frs.w;
            float q0 = sG * fes.x, q1 = sG * fes.y, q2 = sG * fes.z, q3 = sG * fes.w;
            #pragma unroll
            for (int m = 1; m < 32; m <<= 1) {
                p0 += __shfl_xor(p0, m); p1 += __shfl_xor(p1, m);
                p2 += __shfl_xor(p2, m); p3 += __shfl_xor(p3, m);
                q0 += __shfl_xor(q0, m); q1 += __shfl_xor(q1, m);
                q2 += __shfl_xor(q2, m); q3 += __shfl_xor(q3, m);
            }
            int h = lane & 3;
            float esh  = (h & 2) ? ((h & 1) ? p3 : p2) : ((h & 1) ? p1 : p0);
            float esgh = (h & 2) ? ((h & 1) ? q3 : q2) : ((h & 1) ? q1 : q0);
            esh  += prep[640 + l * 4 + h];
            esgh += prep[648 + l * 4 + h];
            if (lane < 4) esgp[lane] = esgh;
            float er = prep[l * 64 + lane];
            float ex = __expf(lrelu(er + esh));
            float s = ex;
            s += __shfl_xor(s, 4); s += __shfl_xor(s, 8);
            s += __shfl_xor(s, 16); s += __shfl_xor(s, 32);
            rap[lane] = ex / s;
        }
        __syncthreads();   // B1: hp/eh/et/rap/esg ready

        // ---- X2: zero U; edge exp + den; prefetch pass-0 B-frags ----
        for (int i = t; i < 1650; i += 512) ((uint4*)(smem + S_U))[i] = make_uint4(0, 0, 0, 0);
        float4 esg4 = *(const float4*)esgp;
        #pragma unroll
        for (int k = 0; k < 4; ++k) {
            int m = em[k];
            if (m >= 0) {
                int s = m & 127, d = (m >> 7) & 127;
                float4 eh4 = *(const float4*)&ehp[s * 4];
                float4 et4 = *(const float4*)&etp[d * 4];
                float x0 = __expf(lrelu(eh4.x + et4.x + esg4.x));
                float x1 = __expf(lrelu(eh4.y + et4.y + esg4.y));
                float x2 = __expf(lrelu(eh4.z + et4.z + esg4.z));
                float x3 = __expf(lrelu(eh4.w + et4.w + esg4.w));
                cc[k][0] = x0; cc[k][1] = x1; cc[k][2] = x2; cc[k][3] = x3;
                atomicAdd(&denp[d * 4 + 0], x0);
                atomicAdd(&denp[d * 4 + 1], x1);
                atomicAdd(&denp[d * 4 + 2], x2);
                atomicAdd(&denp[d * 4 + 3], x3);
            }
        }
        uint4 bfA[4], bfB[4];
        #pragma unroll
        for (int kq = 0; kq < 4; ++kq) {
            bfA[kq] = wf[((l * 16 + kq) * 2 + NtA) * 64 + lane];
            if (hasB) bfB[kq] = wf[((l * 16 + kq) * 2 + NtB) * 64 + lane];
        }
        __syncthreads();   // B2: den final, U zeroed

        // ---- X3: final coefficients (+ att outputs on layer 1); scatter pass 0 ----
        #pragma unroll
        for (int k = 0; k < 4; ++k) {
            int m = em[k];
            if (m >= 0) {
                int d = (m >> 7) & 127, r = (m >> 14) & 15;
                float4 dn = *(const float4*)&denp[d * 4];
                float4 r4 = *(const float4*)&rap[r * 4];
                float a0 = cc[k][0] / dn.x, a1 = cc[k][1] / dn.y;
                float a2 = cc[k][2] / dn.z, a3 = cc[k][3] / dn.w;
                if (l == 1) {
                    int oe = orig[gbase + t + k * 512];
                    *(float4*)&edgeOut[(size_t)oe * 4] = make_float4(a0, a1, a2, a3);
                    *(float4*)&relOut[(size_t)oe * 4] = r4;
                }
                cc[k][0] = a0 * r4.x; cc[k][1] = a1 * r4.y;
                cc[k][2] = a2 * r4.z; cc[k][3] = a3 * r4.w;
            }
        }
        scatterPass(0);
        __syncthreads();   // B3: U(0) scattered

        // ---- P7: 4 passes of MFMA over relation quads ----
        f32x4 accA = {0.f, 0.f, 0.f, 0.f};
        f32x4 accB = {0.f, 0.f, 0.f, 0.f};
        for (int p = 0; p < 4; ++p) {
            #pragma unroll
            for (int kq = 0; kq < 4; ++kq) {
                {
                    const __half* up = Uh + (MtA * 16 + ln15) * 132 + kq * 32 + q8;
                    f16x8 af = two_u2(*(const uint2*)up, *(const uint2*)(up + 4));
                    accA = __builtin_amdgcn_mfma_f32_16x16x32_f16(af, u4_to_f16x8(bfA[kq]), accA, 0, 0, 0);
                }
                if (hasB) {
                    const __half* up = Uh + (MtB * 16 + ln15) * 132 + kq * 32 + q8;
                    f16x8 af = two_u2(*(const uint2*)up, *(const uint2*)(up + 4));
                    accB = __builtin_amdgcn_mfma_f32_16x16x32_f16(af, u4_to_f16x8(bfB[kq]), accB, 0, 0, 0);
                }
            }
            if (p < 3) {
                #pragma unroll
                for (int kq = 0; kq < 4; ++kq) {
                    bfA[kq] = wf[((l * 16 + (p + 1) * 4 + kq) * 2 + NtA) * 64 + lane];
                    if (hasB) bfB[kq] = wf[((l * 16 + (p + 1) * 4 + kq) * 2 + NtB) * 64 + lane];
                }
                __syncthreads();   // U consumed by all waves
                for (int i = t; i < 1650; i += 512) ((uint4*)(smem + S_U))[i] = make_uint4(0, 0, 0, 0);
                __syncthreads();   // U zeroed
                scatterPass(p + 1);
                __syncthreads();   // scattered
            } else {
                // P8: h = relu(0.5*(agg+bias) + 0.5*h); zero eh/et/den for next layer
                if (l == 0)
                    for (int i = t; i < 300; i += 512) ((uint4*)(smem + S_EH))[i] = make_uint4(0, 0, 0, 0);
                {
                    int dcol = NtA * 16 + ln15;
                    float bias = h_bias[l * 32 + dcol];
                    #pragma unroll
                    for (int i = 0; i < 4; ++i) {
                        int n = MtA * 16 + q * 4 + i;
                        if (n < 100) {
                            float hold = __half2float(hH[n * 40 + dcol]);
                            float hn = fmaxf(0.f, 0.5f * (accA[i] + bias) + 0.5f * hold);
                            hH[n * 40 + dcol] = __float2half(hn);
                        }
                    }
                }
                if (hasB) {
                    int dcol = NtB * 16 + ln15;
                    float bias = h_bias[l * 32 + dcol];
                    #pragma unroll
                    for (int i = 0; i < 4; ++i) {
                        int n = MtB * 16 + q * 4 + i;
                        if (n < 100) {
                            float hold = __half2float(hH[n * 40 + dcol]);
                            float hn = fmaxf(0.f, 0.5f * (accB[i] + bias) + 0.5f * hold);
                            hH[n * 40 + dcol] = __float2half(hn);
                        }
                    }
                }
            }
        }
    }
    __syncthreads();   // h final

    // P9: readout x[g] = sum_n h[n] * rw[n]   (red buffer reuses U region)
    float* redp = (float*)(smem + S_U);
    {
        int part = t >> 5, d = t & 31;
        float acc = 0.f;
        for (int n = part; n < 100; n += 16)
            acc += __half2float(hH[n * 40 + d]) * rw[g * 100 + n];
        redp[part * 32 + d] = acc;
    }
    __syncthreads();
    if (t < 32) {
        float s = 0.f;
        #pragma unroll
        for (int p = 0; p < 16; ++p) s += redp[p * 32 + t];
        xout[g * 32 + t] = s;
    }
}

extern "C" void kernel_launch(void* const* d_in, const int* in_sizes, int n_in,
                              void* d_out, int out_size, void* d_ws, size_t ws_size,
                              hipStream_t stream) {
    const float* state     = (const float*)d_in[0];
    const float* rw        = (const float*)d_in[1];
    const float* code_emb  = (const float*)d_in[2];
    const float* rel_table = (const float*)d_in[3];
    const float* W         = (const float*)d_in[4];
    const float* h_bias    = (const float*)d_in[5];
    const float* Wr        = (const float*)d_in[6];
    const float* br        = (const float*)d_in[7];
    const float* We        = (const float*)d_in[8];
    const float* be        = (const float*)d_in[9];
    const float* attn_h    = (const float*)d_in[10];
    const float* attn_t    = (const float*)d_in[11];
    const float* attn_s    = (const float*)d_in[12];
    const float* attn_r    = (const float*)d_in[13];
    const float* attn_rs   = (const float*)d_in[14];
    const int* node_ids    = (const int*)d_in[15];
    const int* src         = (const int*)d_in[16];
    const int* dst         = (const int*)d_in[17];
    const int* rtype       = (const int*)d_in[18];

    float* out = (float*)d_out;
    float* xout = out;
    float* relOut = out + (size_t)NGRAPH * 32;
    float* edgeOut = relOut + (size_t)EDGES * 4;

    int* wsi = (int*)d_ws;
    float* wsf = (float*)d_ws;
    int* hist = wsi + WI_HIST;
    int* off  = wsi + WI_OFF;
    int* curs = wsi + WI_CURS;
    int* meta = wsi + WI_META;
    int* orig = wsi + WI_ORIG;
    float* prep = wsf + WF_PREP;
    uint4* wfrag = (uint4*)(wsf + WF_WFRAG);

    k_zero<<<1, 512, 0, stream>>>(hist);
    k_hist<<<(EDGES + 1023) / 1024, 1024, 0, stream>>>(dst, hist);
    k_scan<<<1, 512, 0, stream>>>(hist, off, curs);
    k_scatter<<<(EDGES + 255) / 256, 256, 0, stream>>>(src, dst, rtype, curs, meta, orig);
    k_setup<<<21, 256, 0, stream>>>(rel_table, Wr, br, We, be, attn_r, attn_rs, attn_s,
                                    W, prep, wfrag);

    (void)hipFuncSetAttribute((const void*)k_fused, hipFuncAttributeMaxDynamicSharedMemorySize, S_TOTAL);
    k_fused<<<NGRAPH, 512, S_TOTAL, stream>>>(state, rw, code_emb, h_bias, be,
                                              attn_h, attn_t, node_ids, off, meta, orig,
                                              prep, wfrag, xout, relOut, edgeOut);
}

// Round 7
// 874.485 us; speedup vs baseline: 1.0966x; 1.0966x over previous
//
#include <hip/hip_runtime.h>
#include <hip/hip_fp16.h>

#define DI __device__ __forceinline__

constexpr int NGRAPH = 500;
constexpr int EDGES  = 800000;
constexpr int C4CAP  = 1920;

// ---- workspace layout (4-byte units) ----
constexpr size_t WI_HIST = 0;                    // [500]
constexpr size_t WI_OFF  = 512;                  // [501]
constexpr size_t WI_CURS = 1024;                 // [500]
constexpr size_t WI_META = 1536;                 // [E]
constexpr size_t WI_ORIG = WI_META + EDGES;      // [E]
constexpr size_t WF_PREP = WI_ORIG + EDGES;      // 656 floats (16B aligned)
constexpr size_t WF_WFRAG = WF_PREP + 672;       // uint4[5120]: W-frags[4096] + We-frags[1024]

// ---- LDS layout (bytes), total 80432 <= 81920 (2 blocks/CU) ----
constexpr int S_H   = 0;       // f16 h[100][40]   (cols 0..31 used)
constexpr int S_HP  = 8000;    // f16 hp[100][128] (col c -> d=c>>2, h=c&3), XOR-swizzled
constexpr int S_U   = 33600;   // f16 U[100][132]  (4 rels x 32 dims + pad)
constexpr int S_EH  = 60000;   // f32[100][4]
constexpr int S_ET  = 61600;   // f32[100][4]
constexpr int S_DEN = 63200;   // f32[100][4]
constexpr int S_RA  = 64800;   // f32[16][4]
constexpr int S_ESG = 65056;   // f32[4]
constexpr int S_C4  = 65072;   // uint2[1920] edge coefficients (f16x4)
constexpr int S_TOTAL = S_C4 + C4CAP * 8;   // 80432

typedef _Float16 f16x8 __attribute__((ext_vector_type(8)));
typedef float f32x4 __attribute__((ext_vector_type(4)));

DI float lrelu(float x) { return x >= 0.f ? x : 0.2f * x; }
DI f16x8 u4_to_f16x8(uint4 u) { f16x8 r; __builtin_memcpy(&r, &u, 16); return r; }
DI f16x8 two_u2(uint2 a, uint2 b) { return u4_to_f16x8(make_uint4(a.x, a.y, b.x, b.y)); }

// hp swizzle: half-index for (node n, col c); XOR bits 3..5 with n&7 (16B granularity)
DI int hpIdx(int n, int c) { return n * 128 + (c ^ ((n & 7) << 3)); }

// packed f16 LDS atomic add (ds_pk_add_f16)
DI void ldsPkAddF16(__half* p, float v0, float v1) {
    __half2 hv = __floats2half2_rn(v0, v1);
    unsigned uv; __builtin_memcpy(&uv, &hv, 4);
    unsigned addr = (unsigned)(unsigned long long)p;
    asm volatile("ds_pk_add_f16 %0, %1" :: "v"(addr), "v"(uv) : "memory");
}

// ---------------- binning (graph-only bins) ----------------
__global__ void k_zero(int* hist) {
    int i = threadIdx.x;
    if (i < NGRAPH) hist[i] = 0;
}

__global__ void k_hist(const int* __restrict__ dst, int* __restrict__ hist) {
    int e = blockIdx.x * 1024 + threadIdx.x;
    if (e < EDGES) atomicAdd(&hist[(unsigned)dst[e] / 100u], 1);
}

__global__ void k_scan(const int* __restrict__ hist, int* __restrict__ off,
                       int* __restrict__ curs) {
    __shared__ int sc[512];
    int t = threadIdx.x;
    int v = (t < NGRAPH) ? hist[t] : 0;
    sc[t] = v;
    __syncthreads();
    for (int o = 1; o < 512; o <<= 1) {
        int a = (t >= o) ? sc[t - o] : 0;
        __syncthreads();
        sc[t] += a;
        __syncthreads();
    }
    int excl = sc[t] - v;
    if (t < NGRAPH) { off[t] = excl; curs[t] = excl; }
    if (t == 0) off[NGRAPH] = EDGES;
}

__global__ void k_scatter(const int* __restrict__ src, const int* __restrict__ dst,
                          const int* __restrict__ rt, int* __restrict__ curs,
                          int* __restrict__ meta, int* __restrict__ orig) {
    int e = blockIdx.x * 256 + threadIdx.x;
    if (e >= EDGES) return;
    int s = src[e], d = dst[e], r = rt[e];
    int g = (unsigned)d / 100u;
    int pos = atomicAdd(&curs[g], 1);
    meta[pos] = (s - g * 100) | ((d - g * 100) << 7) | (r << 14);
    orig[pos] = e;
}

// ---------------- setup: prep folds + f16 MFMA fragments ----------------
__global__ void k_setup(const float* __restrict__ rel_table, const float* __restrict__ Wr,
                        const float* __restrict__ br, const float* __restrict__ We,
                        const float* __restrict__ be, const float* __restrict__ attn_r,
                        const float* __restrict__ attn_rs, const float* __restrict__ attn_s,
                        const float* __restrict__ W, float* __restrict__ prep,
                        uint4* __restrict__ wf) {
    __shared__ float wra[2][32][4];
    __shared__ float sbias[2][3][4];
    int b = blockIdx.x, t = threadIdx.x;
    if (b == 0) {
        {
            int l = t >> 7, k = (t >> 2) & 31, h = t & 3;
            float a = 0.f, bb = 0.f, c = 0.f;
            for (int d2 = 0; d2 < 32; ++d2) {
                float w1 = Wr[(size_t)(l*32 + k)*128 + h*32 + d2];
                float w2 = We[(size_t)(l*32 + k)*128 + h*32 + d2];
                a  += w1 * attn_r [l*128 + h*32 + d2];
                bb += w1 * attn_rs[l*128 + h*32 + d2];
                c  += w2 * attn_s [l*128 + h*32 + d2];
            }
            wra[l][k][h] = a;
            prep[128 + (l*32 + k)*4 + h] = bb;
            prep[384 + (l*32 + k)*4 + h] = c;
        }
        if (t < 24) {
            int l = t / 12, which = (t % 12) / 4, h = t % 4;
            const float* bp = (which == 2) ? be : br;
            const float* ap = (which == 0) ? attn_r : (which == 1 ? attn_rs : attn_s);
            float s = 0.f;
            for (int d2 = 0; d2 < 32; ++d2) s += bp[l*128 + h*32 + d2] * ap[l*128 + h*32 + d2];
            sbias[l][which][h] = s;
        }
        __syncthreads();
        if (t < 128) {
            int l = t >> 6, r = (t >> 2) & 15, h = t & 3;
            float s = sbias[l][0][h];
            for (int k = 0; k < 32; ++k) s += rel_table[r*32 + k] * wra[l][k][h];
            prep[(l*16 + r)*4 + h] = s;
        }
        if (t < 8) {
            int l = t >> 2, h = t & 3;
            prep[640 + l*4 + h] = sbias[l][1][h];
            prep[648 + l*4 + h] = sbias[l][2][h];
        }
    } else if (b <= 16) {
        // W fragments (f16): wf[((l*16+rel)*2+Nt)*64 + ln]
        int fi = (b - 1) * 256 + t;
        int ln = fi & 63, Nt = (fi >> 6) & 1, rel = (fi >> 7) & 15, l = fi >> 11;
        int j = Nt*16 + (ln & 15), k0 = (ln >> 4) << 3;
        unsigned short fr[8];
        #pragma unroll
        for (int i = 0; i < 8; ++i) {
            __half hv = __float2half(W[(((size_t)l*16 + rel)*32 + k0 + i)*32 + j]);
            __builtin_memcpy(&fr[i], &hv, 2);
        }
        uint4 o;
        o.x = fr[0] | ((unsigned)fr[1] << 16);
        o.y = fr[2] | ((unsigned)fr[3] << 16);
        o.z = fr[4] | ((unsigned)fr[5] << 16);
        o.w = fr[6] | ((unsigned)fr[7] << 16);
        wf[fi] = o;
    } else {
        // We fragments (f16, column-permuted): col c -> phys (c&3)*32+(c>>2)
        int fi = (b - 17) * 256 + t;
        int ln = fi & 63, Nt = (fi >> 6) & 7, l = fi >> 9;
        int c = Nt*16 + (ln & 15);
        int phys = (c & 3)*32 + (c >> 2);
        int k0 = (ln >> 4) << 3;
        unsigned short fr[8];
        #pragma unroll
        for (int i = 0; i < 8; ++i) {
            __half hv = __float2half(We[(size_t)l*4096 + (k0 + i)*128 + phys]);
            __builtin_memcpy(&fr[i], &hv, 2);
        }
        uint4 o;
        o.x = fr[0] | ((unsigned)fr[1] << 16);
        o.y = fr[2] | ((unsigned)fr[3] << 16);
        o.z = fr[4] | ((unsigned)fr[5] << 16);
        o.w = fr[6] | ((unsigned)fr[7] << 16);
        wf[4096 + fi] = o;
    }
}

// ---------------- fused per-graph forward ----------------
__global__ void __launch_bounds__(512, 4)
k_fused(const float* __restrict__ state, const float* __restrict__ rw,
        const float* __restrict__ code_emb, const float* __restrict__ h_bias,
        const float* __restrict__ be, const float* __restrict__ attn_h,
        const float* __restrict__ attn_t, const int* __restrict__ node_ids,
        const int* __restrict__ off, const int* __restrict__ meta,
        const int* __restrict__ orig, const float* __restrict__ prep,
        const uint4* __restrict__ wf,
        float* __restrict__ xout, float* __restrict__ relOut, float* __restrict__ edgeOut) {
    extern __shared__ char smem[];
    __half* hH  = (__half*)(smem + S_H);
    __half* hpH = (__half*)(smem + S_HP);
    __half* Uh  = (__half*)(smem + S_U);
    float* ehp  = (float*)(smem + S_EH);
    float* etp  = (float*)(smem + S_ET);
    float* denp = (float*)(smem + S_DEN);
    float* rap  = (float*)(smem + S_RA);
    float* esgp = (float*)(smem + S_ESG);
    uint2* c4p  = (uint2*)(smem + S_C4);
    const uint4* wfe = wf + 4096;

    const int g = blockIdx.x;
    const int t = threadIdx.x;
    const int lane = t & 63, w = t >> 6;
    const int ln15 = lane & 15, q = lane >> 4, q8 = q << 3;
    const int MtA = w % 7, NtA = w / 7;
    const int MtB = (w + 8) % 7, NtB = (w + 8) / 7;
    const bool hasB = (w < 6);
    const int colc = w * 16 + ln15;
    const int physc = (colc & 3) * 32 + (colc >> 2);

    const int gbase = off[g];
    const int ecnt  = off[g + 1] - gbase;

    // P0: h0 = code_emb[node_ids] (f16, [100][40]); zero eh/et/den
    for (int i = t; i < 1600; i += 512) {
        int n = i >> 4, dp = i & 15;
        int id = node_ids[g * 100 + n];
        float2 v = *(const float2*)&code_emb[(size_t)id * 32 + dp * 2];
        *(__half2*)&hH[n * 40 + dp * 2] = __floats2half2_rn(v.x, v.y);
    }
    for (int i = t; i < 300; i += 512) ((uint4*)(smem + S_EH))[i] = make_uint4(0, 0, 0, 0);

    // edge meta -> registers (4 slots per thread); coefficients live in LDS c4
    int em[4];
    #pragma unroll
    for (int k = 0; k < 4; ++k) {
        int e = t + k * 512;
        em[k] = (e < ecnt && e < C4CAP) ? meta[gbase + e] : -1;
    }

    auto scatterPass = [&](int p) {
        #pragma unroll
        for (int k = 0; k < 4; ++k) {
            int m = em[k];
            if (m >= 0 && ((m >> 16) & 3) == p) {
                int s = m & 127, d = (m >> 7) & 127;
                int cb = ((m >> 14) & 3) * 32;
                int sw = (s & 7) << 3;
                uint2 cv = c4p[t + k * 512];
                float2 c01 = __half22float2(*(const __half2*)&cv.x);
                float2 c23 = __half22float2(*(const __half2*)&cv.y);
                float c0 = c01.x, c1 = c01.y, c2 = c23.x, c3 = c23.y;
                #pragma unroll
                for (int db = 0; db < 16; ++db) {
                    uint4 hv = *(const uint4*)&hpH[s * 128 + ((db * 8) ^ sw)];
                    float2 f01 = __half22float2(*(const __half2*)&hv.x);
                    float2 f23 = __half22float2(*(const __half2*)&hv.y);
                    float2 f45 = __half22float2(*(const __half2*)&hv.z);
                    float2 f67 = __half22float2(*(const __half2*)&hv.w);
                    float v0 = c0*f01.x + c1*f01.y + c2*f23.x + c3*f23.y;
                    float v1 = c0*f45.x + c1*f45.y + c2*f67.x + c3*f67.y;
                    ldsPkAddF16(Uh + d * 132 + cb + db * 2, v0, v1);
                }
            }
        }
    };

    for (int l = 0; l < 2; ++l) {
        __syncthreads();   // B0: h ready, eh/et/den zeroed

        // ---- X1: P2-MFMA (hp = h@We + be) + eh/et epilogue (2-deep pipeline) ----
        {
            uint4 bwe = wfe[(l * 8 + w) * 64 + lane];
            f16x8 bw = u4_to_f16x8(bwe);
            float beC = be[l * 128 + physc];
            float ahC = attn_h[l * 128 + physc];
            float atC = attn_t[l * 128 + physc];
            f32x4 z = {0.f, 0.f, 0.f, 0.f};
            const __half* hr0 = hH + ln15 * 40 + q8;
            f32x4 pcur = __builtin_amdgcn_mfma_f32_16x16x32_f16(
                two_u2(*(const uint2*)hr0, *(const uint2*)(hr0 + 4)), bw, z, 0, 0, 0);
            #pragma unroll
            for (int Mt = 0; Mt < 7; ++Mt) {
                f32x4 pnxt;
                if (Mt < 6) {
                    const __half* hr = hH + ((Mt + 1) * 16 + ln15) * 40 + q8;
                    pnxt = __builtin_amdgcn_mfma_f32_16x16x32_f16(
                        two_u2(*(const uint2*)hr, *(const uint2*)(hr + 4)), bw, z, 0, 0, 0);
                }
                #pragma unroll
                for (int i = 0; i < 4; ++i) {
                    int n = Mt * 16 + q * 4 + i;
                    float hv = pcur[i] + beC;
                    bool ok = (n < 100);
                    if (ok) hpH[hpIdx(n, colc)] = __float2half(hv);
                    float veh = ok ? hv * ahC : 0.f;
                    float vet = ok ? hv * atC : 0.f;
                    veh += __shfl_xor(veh, 4); vet += __shfl_xor(vet, 4);
                    veh += __shfl_xor(veh, 8); vet += __shfl_xor(vet, 8);
                    if (ok && (ln15 & 12) == 0) {
                        atomicAdd(&ehp[n * 4 + (ln15 & 3)], veh);
                        atomicAdd(&etp[n * 4 + (ln15 & 3)], vet);
                    }
                }
                pcur = pnxt;
            }
        }
        {   // P1: relation attention (all waves redundantly)
            int k32 = lane & 31;
            float sG = state[g * 32 + k32];
            float4 frs = *(const float4*)&prep[128 + l * 128 + k32 * 4];
            float4 fes = *(const float4*)&prep[384 + l * 128 + k32 * 4];
            float p0 = sG * frs.x, p1 = sG * frs.y, p2 = sG * frs.z, p3 = sG * frs.w;
            float q0 = sG * fes.x, q1 = sG * fes.y, q2 = sG * fes.z, q3 = sG * fes.w;
            #pragma unroll
            for (int m = 1; m < 32; m <<= 1) {
                p0 += __shfl_xor(p0, m); p1 += __shfl_xor(p1, m);
                p2 += __shfl_xor(p2, m); p3 += __shfl_xor(p3, m);
                q0 += __shfl_xor(q0, m); q1 += __shfl_xor(q1, m);
                q2 += __shfl_xor(q2, m); q3 += __shfl_xor(q3, m);
            }
            int h = lane & 3;
            float esh  = (h & 2) ? ((h & 1) ? p3 : p2) : ((h & 1) ? p1 : p0);
            float esgh = (h & 2) ? ((h & 1) ? q3 : q2) : ((h & 1) ? q1 : q0);
            esh  += prep[640 + l * 4 + h];
            esgh += prep[648 + l * 4 + h];
            if (lane < 4) esgp[lane] = esgh;
            float er = prep[l * 64 + lane];
            float ex = __expf(lrelu(er + esh));
            float s = ex;
            s += __shfl_xor(s, 4); s += __shfl_xor(s, 8);
            s += __shfl_xor(s, 16); s += __shfl_xor(s, 32);
            rap[lane] = ex / s;
        }
        __syncthreads();   // B1: hp/eh/et/rap/esg ready

        // ---- X2: zero U; edge exp -> den + c4; prefetch pass-0 B-frags ----
        for (int i = t; i < 1650; i += 512) ((uint4*)(smem + S_U))[i] = make_uint4(0, 0, 0, 0);
        float4 esg4 = *(const float4*)esgp;
        #pragma unroll
        for (int k = 0; k < 4; ++k) {
            int m = em[k];
            if (m >= 0) {
                int s = m & 127, d = (m >> 7) & 127;
                float4 eh4 = *(const float4*)&ehp[s * 4];
                float4 et4 = *(const float4*)&etp[d * 4];
                float x0 = __expf(lrelu(eh4.x + et4.x + esg4.x));
                float x1 = __expf(lrelu(eh4.y + et4.y + esg4.y));
                float x2 = __expf(lrelu(eh4.z + et4.z + esg4.z));
                float x3 = __expf(lrelu(eh4.w + et4.w + esg4.w));
                atomicAdd(&denp[d * 4 + 0], x0);
                atomicAdd(&denp[d * 4 + 1], x1);
                atomicAdd(&denp[d * 4 + 2], x2);
                atomicAdd(&denp[d * 4 + 3], x3);
                __half2 p01 = __floats2half2_rn(x0, x1);
                __half2 p23 = __floats2half2_rn(x2, x3);
                unsigned u01, u23;
                __builtin_memcpy(&u01, &p01, 4); __builtin_memcpy(&u23, &p23, 4);
                c4p[t + k * 512] = make_uint2(u01, u23);
            }
        }
        uint4 bfA[4], bfB[4];
        #pragma unroll
        for (int kq = 0; kq < 4; ++kq) {
            bfA[kq] = wf[((l * 16 + kq) * 2 + NtA) * 64 + lane];
            if (hasB) bfB[kq] = wf[((l * 16 + kq) * 2 + NtB) * 64 + lane];
        }
        __syncthreads();   // B2: den final, U zeroed

        // ---- X3: final coefficients (+ att outputs on layer 1); scatter pass 0 ----
        #pragma unroll
        for (int k = 0; k < 4; ++k) {
            int m = em[k];
            if (m >= 0) {
                int d = (m >> 7) & 127, r = (m >> 14) & 15;
                uint2 cv = c4p[t + k * 512];
                float2 x01 = __half22float2(*(const __half2*)&cv.x);
                float2 x23 = __half22float2(*(const __half2*)&cv.y);
                float4 dn = *(const float4*)&denp[d * 4];
                float4 r4 = *(const float4*)&rap[r * 4];
                float a0 = x01.x / dn.x, a1 = x01.y / dn.y;
                float a2 = x23.x / dn.z, a3 = x23.y / dn.w;
                if (l == 1) {
                    int oe = orig[gbase + t + k * 512];
                    *(float4*)&edgeOut[(size_t)oe * 4] = make_float4(a0, a1, a2, a3);
                    *(float4*)&relOut[(size_t)oe * 4] = r4;
                }
                __half2 c01 = __floats2half2_rn(a0 * r4.x, a1 * r4.y);
                __half2 c23 = __floats2half2_rn(a2 * r4.z, a3 * r4.w);
                unsigned u01, u23;
                __builtin_memcpy(&u01, &c01, 4); __builtin_memcpy(&u23, &c23, 4);
                c4p[t + k * 512] = make_uint2(u01, u23);
            }
        }
        scatterPass(0);
        __syncthreads();   // B3: U(0) scattered

        // ---- P7: 4 passes of MFMA over relation quads ----
        f32x4 accA = {0.f, 0.f, 0.f, 0.f};
        f32x4 accB = {0.f, 0.f, 0.f, 0.f};
        for (int p = 0; p < 4; ++p) {
            #pragma unroll
            for (int kq = 0; kq < 4; ++kq) {
                {
                    const __half* up = Uh + (MtA * 16 + ln15) * 132 + kq * 32 + q8;
                    f16x8 af = two_u2(*(const uint2*)up, *(const uint2*)(up + 4));
                    accA = __builtin_amdgcn_mfma_f32_16x16x32_f16(af, u4_to_f16x8(bfA[kq]), accA, 0, 0, 0);
                }
                if (hasB) {
                    const __half* up = Uh + (MtB * 16 + ln15) * 132 + kq * 32 + q8;
                    f16x8 af = two_u2(*(const uint2*)up, *(const uint2*)(up + 4));
                    accB = __builtin_amdgcn_mfma_f32_16x16x32_f16(af, u4_to_f16x8(bfB[kq]), accB, 0, 0, 0);
                }
            }
            if (p < 3) {
                #pragma unroll
                for (int kq = 0; kq < 4; ++kq) {
                    bfA[kq] = wf[((l * 16 + (p + 1) * 4 + kq) * 2 + NtA) * 64 + lane];
                    if (hasB) bfB[kq] = wf[((l * 16 + (p + 1) * 4 + kq) * 2 + NtB) * 64 + lane];
                }
                __syncthreads();   // U consumed by all waves
                for (int i = t; i < 1650; i += 512) ((uint4*)(smem + S_U))[i] = make_uint4(0, 0, 0, 0);
                __syncthreads();   // U zeroed
                scatterPass(p + 1);
                __syncthreads();   // scattered
            } else {
                // P8: h = relu(0.5*(agg+bias) + 0.5*h); zero eh/et/den for next layer
                if (l == 0)
                    for (int i = t; i < 300; i += 512) ((uint4*)(smem + S_EH))[i] = make_uint4(0, 0, 0, 0);
                {
                    int dcol = NtA * 16 + ln15;
                    float bias = h_bias[l * 32 + dcol];
                    #pragma unroll
                    for (int i = 0; i < 4; ++i) {
                        int n = MtA * 16 + q * 4 + i;
                        if (n < 100) {
                            float hold = __half2float(hH[n * 40 + dcol]);
                            float hn = fmaxf(0.f, 0.5f * (accA[i] + bias) + 0.5f * hold);
                            hH[n * 40 + dcol] = __float2half(hn);
                        }
                    }
                }
                if (hasB) {
                    int dcol = NtB * 16 + ln15;
                    float bias = h_bias[l * 32 + dcol];
                    #pragma unroll
                    for (int i = 0; i < 4; ++i) {
                        int n = MtB * 16 + q * 4 + i;
                        if (n < 100) {
                            float hold = __half2float(hH[n * 40 + dcol]);
                            float hn = fmaxf(0.f, 0.5f * (accB[i] + bias) + 0.5f * hold);
                            hH[n * 40 + dcol] = __float2half(hn);
                        }
                    }
                }
            }
        }
    }
    __syncthreads();   // h final

    // P9: readout x[g] = sum_n h[n] * rw[n]   (red buffer reuses U region)
    float* redp = (float*)(smem + S_U);
    {
        int part = t >> 5, d = t & 31;
        float acc = 0.f;
        for (int n = part; n < 100; n += 16)
            acc += __half2float(hH[n * 40 + d]) * rw[g * 100 + n];
        redp[part * 32 + d] = acc;
    }
    __syncthreads();
    if (t < 32) {
        float s = 0.f;
        #pragma unroll
        for (int p = 0; p < 16; ++p) s += redp[p * 32 + t];
        xout[g * 32 + t] = s;
    }
}

extern "C" void kernel_launch(void* const* d_in, const int* in_sizes, int n_in,
                              void* d_out, int out_size, void* d_ws, size_t ws_size,
                              hipStream_t stream) {
    const float* state     = (const float*)d_in[0];
    const float* rw        = (const float*)d_in[1];
    const float* code_emb  = (const float*)d_in[2];
    const float* rel_table = (const float*)d_in[3];
    const float* W         = (const float*)d_in[4];
    const float* h_bias    = (const float*)d_in[5];
    const float* Wr        = (const float*)d_in[6];
    const float* br        = (const float*)d_in[7];
    const float* We        = (const float*)d_in[8];
    const float* be        = (const float*)d_in[9];
    const float* attn_h    = (const float*)d_in[10];
    const float* attn_t    = (const float*)d_in[11];
    const float* attn_s    = (const float*)d_in[12];
    const float* attn_r    = (const float*)d_in[13];
    const float* attn_rs   = (const float*)d_in[14];
    const int* node_ids    = (const int*)d_in[15];
    const int* src         = (const int*)d_in[16];
    const int* dst         = (const int*)d_in[17];
    const int* rtype       = (const int*)d_in[18];

    float* out = (float*)d_out;
    float* xout = out;
    float* relOut = out + (size_t)NGRAPH * 32;
    float* edgeOut = relOut + (size_t)EDGES * 4;

    int* wsi = (int*)d_ws;
    float* wsf = (float*)d_ws;
    int* hist = wsi + WI_HIST;
    int* off  = wsi + WI_OFF;
    int* curs = wsi + WI_CURS;
    int* meta = wsi + WI_META;
    int* orig = wsi + WI_ORIG;
    float* prep = wsf + WF_PREP;
    uint4* wfrag = (uint4*)(wsf + WF_WFRAG);

    k_zero<<<1, 512, 0, stream>>>(hist);
    k_hist<<<(EDGES + 1023) / 1024, 1024, 0, stream>>>(dst, hist);
    k_scan<<<1, 512, 0, stream>>>(hist, off, curs);
    k_scatter<<<(EDGES + 255) / 256, 256, 0, stream>>>(src, dst, rtype, curs, meta, orig);
    k_setup<<<21, 256, 0, stream>>>(rel_table, Wr, br, We, be, attn_r, attn_rs, attn_s,
                                    W, prep, wfrag);

    (void)hipFuncSetAttribute((const void*)k_fused, hipFuncAttributeMaxDynamicSharedMemorySize, S_TOTAL);
    k_fused<<<NGRAPH, 512, S_TOTAL, stream>>>(state, rw, code_emb, h_bias, be,
                                              attn_h, attn_t, node_ids, off, meta, orig,
                                              prep, wfrag, xout, relOut, edgeOut);
}

// Round 8
// 795.415 us; speedup vs baseline: 1.2056x; 1.0994x over previous
//
#include <hip/hip_runtime.h>
#include <hip/hip_fp16.h>

#define DI __device__ __forceinline__

constexpr int NGRAPH = 500;
constexpr int EDGES  = 800000;
constexpr int C4CAP  = 1920;

// ---- workspace layout (4-byte units) ----
constexpr size_t WI_HIST = 0;                    // [500]
constexpr size_t WI_OFF  = 512;                  // [501]
constexpr size_t WI_CURS = 1024;                 // [500]
constexpr size_t WI_META = 1536;                 // [E]
constexpr size_t WI_ORIG = WI_META + EDGES;      // [E]
constexpr size_t WF_PREP = WI_ORIG + EDGES;      // 656 floats (16B aligned)
constexpr size_t WF_WFRAG = WF_PREP + 672;       // uint4[5120]: W-frags[4096] + We-frags[1024]

// ---- LDS layout (bytes), total 80432 <= 81920 (2 blocks/CU) ----
constexpr int S_H   = 0;       // f16 h[100][40]   (cols 0..31 used)
constexpr int S_HP  = 8000;    // f16 hp[100][128] (col c -> d=c>>2, h=c&3), XOR-swizzled
constexpr int S_U   = 33600;   // f16 U[100][132]  (4 rels x 32 dims + pad)
constexpr int S_EH  = 60000;   // f32[100][4]
constexpr int S_ET  = 61600;   // f32[100][4]
constexpr int S_DEN = 63200;   // f32[100][4]
constexpr int S_RA  = 64800;   // f32[16][4]
constexpr int S_ESG = 65056;   // f32[4]
constexpr int S_C4  = 65072;   // uint2[1920] edge coefficients (f16x4)
constexpr int S_TOTAL = S_C4 + C4CAP * 8;   // 80432

typedef _Float16 f16x8 __attribute__((ext_vector_type(8)));
typedef float f32x4 __attribute__((ext_vector_type(4)));

DI float lrelu(float x) { return x >= 0.f ? x : 0.2f * x; }
DI f16x8 u4_to_f16x8(uint4 u) { f16x8 r; __builtin_memcpy(&r, &u, 16); return r; }
DI f16x8 two_u2(uint2 a, uint2 b) { return u4_to_f16x8(make_uint4(a.x, a.y, b.x, b.y)); }

// hp swizzle: half-index for (node n, col c); XOR bits 3..5 with n&7 (16B granularity)
DI int hpIdx(int n, int c) { return n * 128 + (c ^ ((n & 7) << 3)); }

// packed f16 LDS atomic add (ds_pk_add_f16)
DI void ldsPkAddF16(__half* p, float v0, float v1) {
    __half2 hv = __floats2half2_rn(v0, v1);
    unsigned uv; __builtin_memcpy(&uv, &hv, 4);
    unsigned addr = (unsigned)(unsigned long long)p;
    asm volatile("ds_pk_add_f16 %0, %1" :: "v"(addr), "v"(uv) : "memory");
}

// ---------------- binning (graph-only bins) ----------------
__global__ void k_zero(int* hist) {
    int i = threadIdx.x;
    if (i < NGRAPH) hist[i] = 0;
}

__global__ void k_hist(const int* __restrict__ dst, int* __restrict__ hist) {
    int e = blockIdx.x * 1024 + threadIdx.x;
    if (e < EDGES) atomicAdd(&hist[(unsigned)dst[e] / 100u], 1);
}

__global__ void k_scan(const int* __restrict__ hist, int* __restrict__ off,
                       int* __restrict__ curs) {
    __shared__ int sc[512];
    int t = threadIdx.x;
    int v = (t < NGRAPH) ? hist[t] : 0;
    sc[t] = v;
    __syncthreads();
    for (int o = 1; o < 512; o <<= 1) {
        int a = (t >= o) ? sc[t - o] : 0;
        __syncthreads();
        sc[t] += a;
        __syncthreads();
    }
    int excl = sc[t] - v;
    if (t < NGRAPH) { off[t] = excl; curs[t] = excl; }
    if (t == 0) off[NGRAPH] = EDGES;
}

__global__ void k_scatter(const int* __restrict__ src, const int* __restrict__ dst,
                          const int* __restrict__ rt, int* __restrict__ curs,
                          int* __restrict__ meta, int* __restrict__ orig) {
    int e = blockIdx.x * 256 + threadIdx.x;
    if (e >= EDGES) return;
    int s = src[e], d = dst[e], r = rt[e];
    int g = (unsigned)d / 100u;
    int pos = atomicAdd(&curs[g], 1);
    meta[pos] = (s - g * 100) | ((d - g * 100) << 7) | (r << 14);
    orig[pos] = e;
}

// ---------------- setup: prep folds + f16 MFMA fragments ----------------
__global__ void k_setup(const float* __restrict__ rel_table, const float* __restrict__ Wr,
                        const float* __restrict__ br, const float* __restrict__ We,
                        const float* __restrict__ be, const float* __restrict__ attn_r,
                        const float* __restrict__ attn_rs, const float* __restrict__ attn_s,
                        const float* __restrict__ W, float* __restrict__ prep,
                        uint4* __restrict__ wf) {
    __shared__ float wra[2][32][4];
    __shared__ float sbias[2][3][4];
    int b = blockIdx.x, t = threadIdx.x;
    if (b == 0) {
        {
            int l = t >> 7, k = (t >> 2) & 31, h = t & 3;
            float a = 0.f, bb = 0.f, c = 0.f;
            for (int d2 = 0; d2 < 32; ++d2) {
                float w1 = Wr[(size_t)(l*32 + k)*128 + h*32 + d2];
                float w2 = We[(size_t)(l*32 + k)*128 + h*32 + d2];
                a  += w1 * attn_r [l*128 + h*32 + d2];
                bb += w1 * attn_rs[l*128 + h*32 + d2];
                c  += w2 * attn_s [l*128 + h*32 + d2];
            }
            wra[l][k][h] = a;
            prep[128 + (l*32 + k)*4 + h] = bb;
            prep[384 + (l*32 + k)*4 + h] = c;
        }
        if (t < 24) {
            int l = t / 12, which = (t % 12) / 4, h = t % 4;
            const float* bp = (which == 2) ? be : br;
            const float* ap = (which == 0) ? attn_r : (which == 1 ? attn_rs : attn_s);
            float s = 0.f;
            for (int d2 = 0; d2 < 32; ++d2) s += bp[l*128 + h*32 + d2] * ap[l*128 + h*32 + d2];
            sbias[l][which][h] = s;
        }
        __syncthreads();
        if (t < 128) {
            int l = t >> 6, r = (t >> 2) & 15, h = t & 3;
            float s = sbias[l][0][h];
            for (int k = 0; k < 32; ++k) s += rel_table[r*32 + k] * wra[l][k][h];
            prep[(l*16 + r)*4 + h] = s;
        }
        if (t < 8) {
            int l = t >> 2, h = t & 3;
            prep[640 + l*4 + h] = sbias[l][1][h];
            prep[648 + l*4 + h] = sbias[l][2][h];
        }
    } else if (b <= 16) {
        // W fragments (f16): wf[((l*16+rel)*2+Nt)*64 + ln]
        int fi = (b - 1) * 256 + t;
        int ln = fi & 63, Nt = (fi >> 6) & 1, rel = (fi >> 7) & 15, l = fi >> 11;
        int j = Nt*16 + (ln & 15), k0 = (ln >> 4) << 3;
        unsigned short fr[8];
        #pragma unroll
        for (int i = 0; i < 8; ++i) {
            __half hv = __float2half(W[(((size_t)l*16 + rel)*32 + k0 + i)*32 + j]);
            __builtin_memcpy(&fr[i], &hv, 2);
        }
        uint4 o;
        o.x = fr[0] | ((unsigned)fr[1] << 16);
        o.y = fr[2] | ((unsigned)fr[3] << 16);
        o.z = fr[4] | ((unsigned)fr[5] << 16);
        o.w = fr[6] | ((unsigned)fr[7] << 16);
        wf[fi] = o;
    } else {
        // We fragments (f16, column-permuted): col c -> phys (c&3)*32+(c>>2)
        int fi = (b - 17) * 256 + t;
        int ln = fi & 63, Nt = (fi >> 6) & 7, l = fi >> 9;
        int c = Nt*16 + (ln & 15);
        int phys = (c & 3)*32 + (c >> 2);
        int k0 = (ln >> 4) << 3;
        unsigned short fr[8];
        #pragma unroll
        for (int i = 0; i < 8; ++i) {
            __half hv = __float2half(We[(size_t)l*4096 + (k0 + i)*128 + phys]);
            __builtin_memcpy(&fr[i], &hv, 2);
        }
        uint4 o;
        o.x = fr[0] | ((unsigned)fr[1] << 16);
        o.y = fr[2] | ((unsigned)fr[3] << 16);
        o.z = fr[4] | ((unsigned)fr[5] << 16);
        o.w = fr[6] | ((unsigned)fr[7] << 16);
        wf[4096 + fi] = o;
    }
}

// ---------------- fused per-graph forward ----------------
__global__ void __launch_bounds__(512, 2)
k_fused(const float* __restrict__ state, const float* __restrict__ rw,
        const float* __restrict__ code_emb, const float* __restrict__ h_bias,
        const float* __restrict__ be, const float* __restrict__ attn_h,
        const float* __restrict__ attn_t, const int* __restrict__ node_ids,
        const int* __restrict__ off, const int* __restrict__ meta,
        const int* __restrict__ orig, const float* __restrict__ prep,
        const uint4* __restrict__ wf,
        float* __restrict__ xout, float* __restrict__ relOut, float* __restrict__ edgeOut) {
    extern __shared__ char smem[];
    __half* hH  = (__half*)(smem + S_H);
    __half* hpH = (__half*)(smem + S_HP);
    __half* Uh  = (__half*)(smem + S_U);
    float* ehp  = (float*)(smem + S_EH);
    float* etp  = (float*)(smem + S_ET);
    float* denp = (float*)(smem + S_DEN);
    float* rap  = (float*)(smem + S_RA);
    float* esgp = (float*)(smem + S_ESG);
    uint2* c4p  = (uint2*)(smem + S_C4);
    const uint4* wfe = wf + 4096;

    const int g = blockIdx.x;
    const int t = threadIdx.x;
    const int lane = t & 63, w = t >> 6;
    const int ln15 = lane & 15, q = lane >> 4, q8 = q << 3;
    const int MtA = w % 7, NtA = w / 7;
    const int MtB = (w + 8) % 7, NtB = (w + 8) / 7;
    const bool hasB = (w < 6);
    const int colc = w * 16 + ln15;
    const int physc = (colc & 3) * 32 + (colc >> 2);

    const int gbase = off[g];
    const int ecnt  = off[g + 1] - gbase;

    // P0: h0 = code_emb[node_ids] (f16, [100][40]); zero eh/et/den
    for (int i = t; i < 1600; i += 512) {
        int n = i >> 4, dp = i & 15;
        int id = node_ids[g * 100 + n];
        float2 v = *(const float2*)&code_emb[(size_t)id * 32 + dp * 2];
        *(__half2*)&hH[n * 40 + dp * 2] = __floats2half2_rn(v.x, v.y);
    }
    for (int i = t; i < 300; i += 512) ((uint4*)(smem + S_EH))[i] = make_uint4(0, 0, 0, 0);

    // edge meta -> registers (4 slots per thread); coefficients live in LDS c4
    int em[4];
    #pragma unroll
    for (int k = 0; k < 4; ++k) {
        int e = t + k * 512;
        em[k] = (e < ecnt && e < C4CAP) ? meta[gbase + e] : -1;
    }

    auto scatterPass = [&](int p) {
        #pragma unroll
        for (int k = 0; k < 4; ++k) {
            int m = em[k];
            if (m >= 0 && ((m >> 16) & 3) == p) {
                int s = m & 127, d = (m >> 7) & 127;
                int cb = ((m >> 14) & 3) * 32;
                int sw = (s & 7) << 3;
                uint2 cv = c4p[t + k * 512];
                float2 c01 = __half22float2(*(const __half2*)&cv.x);
                float2 c23 = __half22float2(*(const __half2*)&cv.y);
                float c0 = c01.x, c1 = c01.y, c2 = c23.x, c3 = c23.y;
                #pragma unroll
                for (int db = 0; db < 16; ++db) {
                    uint4 hv = *(const uint4*)&hpH[s * 128 + ((db * 8) ^ sw)];
                    float2 f01 = __half22float2(*(const __half2*)&hv.x);
                    float2 f23 = __half22float2(*(const __half2*)&hv.y);
                    float2 f45 = __half22float2(*(const __half2*)&hv.z);
                    float2 f67 = __half22float2(*(const __half2*)&hv.w);
                    float v0 = c0*f01.x + c1*f01.y + c2*f23.x + c3*f23.y;
                    float v1 = c0*f45.x + c1*f45.y + c2*f67.x + c3*f67.y;
                    ldsPkAddF16(Uh + d * 132 + cb + db * 2, v0, v1);
                }
            }
        }
    };

    for (int l = 0; l < 2; ++l) {
        __syncthreads();   // B0: h ready, eh/et/den zeroed

        // ---- X1: P2-MFMA (hp = h@We + be) + eh/et epilogue (2-deep pipeline) ----
        {
            uint4 bwe = wfe[(l * 8 + w) * 64 + lane];
            f16x8 bw = u4_to_f16x8(bwe);
            float beC = be[l * 128 + physc];
            float ahC = attn_h[l * 128 + physc];
            float atC = attn_t[l * 128 + physc];
            f32x4 z = {0.f, 0.f, 0.f, 0.f};
            const __half* hr0 = hH + ln15 * 40 + q8;
            f32x4 pcur = __builtin_amdgcn_mfma_f32_16x16x32_f16(
                two_u2(*(const uint2*)hr0, *(const uint2*)(hr0 + 4)), bw, z, 0, 0, 0);
            #pragma unroll
            for (int Mt = 0; Mt < 7; ++Mt) {
                f32x4 pnxt;
                if (Mt < 6) {
                    const __half* hr = hH + ((Mt + 1) * 16 + ln15) * 40 + q8;
                    pnxt = __builtin_amdgcn_mfma_f32_16x16x32_f16(
                        two_u2(*(const uint2*)hr, *(const uint2*)(hr + 4)), bw, z, 0, 0, 0);
                }
                #pragma unroll
                for (int i = 0; i < 4; ++i) {
                    int n = Mt * 16 + q * 4 + i;
                    float hv = pcur[i] + beC;
                    bool ok = (n < 100);
                    if (ok) hpH[hpIdx(n, colc)] = __float2half(hv);
                    float veh = ok ? hv * ahC : 0.f;
                    float vet = ok ? hv * atC : 0.f;
                    veh += __shfl_xor(veh, 4); vet += __shfl_xor(vet, 4);
                    veh += __shfl_xor(veh, 8); vet += __shfl_xor(vet, 8);
                    if (ok && (ln15 & 12) == 0) {
                        atomicAdd(&ehp[n * 4 + (ln15 & 3)], veh);
                        atomicAdd(&etp[n * 4 + (ln15 & 3)], vet);
                    }
                }
                pcur = pnxt;
            }
        }
        {   // P1: relation attention (all waves redundantly)
            int k32 = lane & 31;
            float sG = state[g * 32 + k32];
            float4 frs = *(const float4*)&prep[128 + l * 128 + k32 * 4];
            float4 fes = *(const float4*)&prep[384 + l * 128 + k32 * 4];
            float p0 = sG * frs.x, p1 = sG * frs.y, p2 = sG * frs.z, p3 = sG * frs.w;
            float q0 = sG * fes.x, q1 = sG * fes.y, q2 = sG * fes.z, q3 = sG * fes.w;
            #pragma unroll
            for (int m = 1; m < 32; m <<= 1) {
                p0 += __shfl_xor(p0, m); p1 += __shfl_xor(p1, m);
                p2 += __shfl_xor(p2, m); p3 += __shfl_xor(p3, m);
                q0 += __shfl_xor(q0, m); q1 += __shfl_xor(q1, m);
                q2 += __shfl_xor(q2, m); q3 += __shfl_xor(q3, m);
            }
            int h = lane & 3;
            float esh  = (h & 2) ? ((h & 1) ? p3 : p2) : ((h & 1) ? p1 : p0);
            float esgh = (h & 2) ? ((h & 1) ? q3 : q2) : ((h & 1) ? q1 : q0);
            esh  += prep[640 + l * 4 + h];
            esgh += prep[648 + l * 4 + h];
            if (lane < 4) esgp[lane] = esgh;
            float er = prep[l * 64 + lane];
            float ex = __expf(lrelu(er + esh));
            float s = ex;
            s += __shfl_xor(s, 4); s += __shfl_xor(s, 8);
            s += __shfl_xor(s, 16); s += __shfl_xor(s, 32);
            rap[lane] = ex / s;
        }
        __syncthreads();   // B1: hp/eh/et/rap/esg ready

        // ---- X2: zero U; edge exp -> den + c4 ----
        for (int i = t; i < 1650; i += 512) ((uint4*)(smem + S_U))[i] = make_uint4(0, 0, 0, 0);
        float4 esg4 = *(const float4*)esgp;
        #pragma unroll
        for (int k = 0; k < 4; ++k) {
            int m = em[k];
            if (m >= 0) {
                int s = m & 127, d = (m >> 7) & 127;
                float4 eh4 = *(const float4*)&ehp[s * 4];
                float4 et4 = *(const float4*)&etp[d * 4];
                float x0 = __expf(lrelu(eh4.x + et4.x + esg4.x));
                float x1 = __expf(lrelu(eh4.y + et4.y + esg4.y));
                float x2 = __expf(lrelu(eh4.z + et4.z + esg4.z));
                float x3 = __expf(lrelu(eh4.w + et4.w + esg4.w));
                atomicAdd(&denp[d * 4 + 0], x0);
                atomicAdd(&denp[d * 4 + 1], x1);
                atomicAdd(&denp[d * 4 + 2], x2);
                atomicAdd(&denp[d * 4 + 3], x3);
                __half2 p01 = __floats2half2_rn(x0, x1);
                __half2 p23 = __floats2half2_rn(x2, x3);
                unsigned u01, u23;
                __builtin_memcpy(&u01, &p01, 4); __builtin_memcpy(&u23, &p23, 4);
                c4p[t + k * 512] = make_uint2(u01, u23);
            }
        }
        __syncthreads();   // B2: den final, U zeroed

        // ---- X3: final coefficients (+ att outputs on layer 1); scatter pass 0 ----
        #pragma unroll
        for (int k = 0; k < 4; ++k) {
            int m = em[k];
            if (m >= 0) {
                int d = (m >> 7) & 127, r = (m >> 14) & 15;
                uint2 cv = c4p[t + k * 512];
                float2 x01 = __half22float2(*(const __half2*)&cv.x);
                float2 x23 = __half22float2(*(const __half2*)&cv.y);
                float4 dn = *(const float4*)&denp[d * 4];
                float4 r4 = *(const float4*)&rap[r * 4];
                float a0 = x01.x / dn.x, a1 = x01.y / dn.y;
                float a2 = x23.x / dn.z, a3 = x23.y / dn.w;
                if (l == 1) {
                    int oe = orig[gbase + t + k * 512];
                    *(float4*)&edgeOut[(size_t)oe * 4] = make_float4(a0, a1, a2, a3);
                    *(float4*)&relOut[(size_t)oe * 4] = r4;
                }
                __half2 c01 = __floats2half2_rn(a0 * r4.x, a1 * r4.y);
                __half2 c23 = __floats2half2_rn(a2 * r4.z, a3 * r4.w);
                unsigned u01, u23;
                __builtin_memcpy(&u01, &c01, 4); __builtin_memcpy(&u23, &c23, 4);
                c4p[t + k * 512] = make_uint2(u01, u23);
            }
        }
        scatterPass(0);
        __syncthreads();   // B3: U(0) scattered

        // ---- P7: 4 passes of MFMA over relation quads (B-frags loaded just-in-time) ----
        f32x4 accA = {0.f, 0.f, 0.f, 0.f};
        f32x4 accB = {0.f, 0.f, 0.f, 0.f};
        for (int p = 0; p < 4; ++p) {
            #pragma unroll
            for (int kq = 0; kq < 4; ++kq) {
                int rel = p * 4 + kq;
                {
                    uint4 bAu = wf[((l * 16 + rel) * 2 + NtA) * 64 + lane];
                    const __half* up = Uh + (MtA * 16 + ln15) * 132 + kq * 32 + q8;
                    f16x8 af = two_u2(*(const uint2*)up, *(const uint2*)(up + 4));
                    accA = __builtin_amdgcn_mfma_f32_16x16x32_f16(af, u4_to_f16x8(bAu), accA, 0, 0, 0);
                }
                if (hasB) {
                    uint4 bBu = wf[((l * 16 + rel) * 2 + NtB) * 64 + lane];
                    const __half* up = Uh + (MtB * 16 + ln15) * 132 + kq * 32 + q8;
                    f16x8 af = two_u2(*(const uint2*)up, *(const uint2*)(up + 4));
                    accB = __builtin_amdgcn_mfma_f32_16x16x32_f16(af, u4_to_f16x8(bBu), accB, 0, 0, 0);
                }
            }
            if (p < 3) {
                __syncthreads();   // U consumed by all waves
                for (int i = t; i < 1650; i += 512) ((uint4*)(smem + S_U))[i] = make_uint4(0, 0, 0, 0);
                __syncthreads();   // U zeroed
                scatterPass(p + 1);
                __syncthreads();   // scattered
            } else {
                // P8: h = relu(0.5*(agg+bias) + 0.5*h); zero eh/et/den for next layer
                if (l == 0)
                    for (int i = t; i < 300; i += 512) ((uint4*)(smem + S_EH))[i] = make_uint4(0, 0, 0, 0);
                {
                    int dcol = NtA * 16 + ln15;
                    float bias = h_bias[l * 32 + dcol];
                    #pragma unroll
                    for (int i = 0; i < 4; ++i) {
                        int n = MtA * 16 + q * 4 + i;
                        if (n < 100) {
                            float hold = __half2float(hH[n * 40 + dcol]);
                            float hn = fmaxf(0.f, 0.5f * (accA[i] + bias) + 0.5f * hold);
                            hH[n * 40 + dcol] = __float2half(hn);
                        }
                    }
                }
                if (hasB) {
                    int dcol = NtB * 16 + ln15;
                    float bias = h_bias[l * 32 + dcol];
                    #pragma unroll
                    for (int i = 0; i < 4; ++i) {
                        int n = MtB * 16 + q * 4 + i;
                        if (n < 100) {
                            float hold = __half2float(hH[n * 40 + dcol]);
                            float hn = fmaxf(0.f, 0.5f * (accB[i] + bias) + 0.5f * hold);
                            hH[n * 40 + dcol] = __float2half(hn);
                        }
                    }
                }
            }
        }
    }
    __syncthreads();   // h final

    // P9: readout x[g] = sum_n h[n] * rw[n]   (red buffer reuses U region)
    float* redp = (float*)(smem + S_U);
    {
        int part = t >> 5, d = t & 31;
        float acc = 0.f;
        for (int n = part; n < 100; n += 16)
            acc += __half2float(hH[n * 40 + d]) * rw[g * 100 + n];
        redp[part * 32 + d] = acc;
    }
    __syncthreads();
    if (t < 32) {
        float s = 0.f;
        #pragma unroll
        for (int p = 0; p < 16; ++p) s += redp[p * 32 + t];
        xout[g * 32 + t] = s;
    }
}

extern "C" void kernel_launch(void* const* d_in, const int* in_sizes, int n_in,
                              void* d_out, int out_size, void* d_ws, size_t ws_size,
                              hipStream_t stream) {
    const float* state     = (const float*)d_in[0];
    const float* rw        = (const float*)d_in[1];
    const float* code_emb  = (const float*)d_in[2];
    const float* rel_table = (const float*)d_in[3];
    const float* W         = (const float*)d_in[4];
    const float* h_bias    = (const float*)d_in[5];
    const float* Wr        = (const float*)d_in[6];
    const float* br        = (const float*)d_in[7];
    const float* We        = (const float*)d_in[8];
    const float* be        = (const float*)d_in[9];
    const float* attn_h    = (const float*)d_in[10];
    const float* attn_t    = (const float*)d_in[11];
    const float* attn_s    = (const float*)d_in[12];
    const float* attn_r    = (const float*)d_in[13];
    const float* attn_rs   = (const float*)d_in[14];
    const int* node_ids    = (const int*)d_in[15];
    const int* src         = (const int*)d_in[16];
    const int* dst         = (const int*)d_in[17];
    const int* rtype       = (const int*)d_in[18];

    float* out = (float*)d_out;
    float* xout = out;
    float* relOut = out + (size_t)NGRAPH * 32;
    float* edgeOut = relOut + (size_t)EDGES * 4;

    int* wsi = (int*)d_ws;
    float* wsf = (float*)d_ws;
    int* hist = wsi + WI_HIST;
    int* off  = wsi + WI_OFF;
    int* curs = wsi + WI_CURS;
    int* meta = wsi + WI_META;
    int* orig = wsi + WI_ORIG;
    float* prep = wsf + WF_PREP;
    uint4* wfrag = (uint4*)(wsf + WF_WFRAG);

    k_zero<<<1, 512, 0, stream>>>(hist);
    k_hist<<<(EDGES + 1023) / 1024, 1024, 0, stream>>>(dst, hist);
    k_scan<<<1, 512, 0, stream>>>(hist, off, curs);
    k_scatter<<<(EDGES + 255) / 256, 256, 0, stream>>>(src, dst, rtype, curs, meta, orig);
    k_setup<<<21, 256, 0, stream>>>(rel_table, Wr, br, We, be, attn_r, attn_rs, attn_s,
                                    W, prep, wfrag);

    (void)hipFuncSetAttribute((const void*)k_fused, hipFuncAttributeMaxDynamicSharedMemorySize, S_TOTAL);
    k_fused<<<NGRAPH, 512, S_TOTAL, stream>>>(state, rw, code_emb, h_bias, be,
                                              attn_h, attn_t, node_ids, off, meta, orig,
                                              prep, wfrag, xout, relOut, edgeOut);
}

// Round 9
// 366.168 us; speedup vs baseline: 2.6189x; 2.1723x over previous
//
#include <hip/hip_runtime.h>
#include <hip/hip_fp16.h>

#define DI __device__ __forceinline__

constexpr int NGRAPH = 500;
constexpr int EDGES  = 800000;
constexpr int NBIN   = NGRAPH * 16;   // (graph, relation)

// ---- workspace layout (4-byte units) ----
constexpr size_t WI_HIST = 0;                    // [8000]
constexpr size_t WI_OFF  = WI_HIST + NBIN;       // [8001]
constexpr size_t WI_CURS = WI_OFF + NBIN + 1;    // [8000]
constexpr size_t WI_META = WI_CURS + NBIN;       // [E]
constexpr size_t WI_ORIG = WI_META + EDGES;      // [E]
constexpr size_t WF_PREP = WI_ORIG + EDGES;      // 656 floats
constexpr size_t WF_WFRAG = WF_PREP + 672;       // uint4[5120]: W-frags[4096] + We-frags[1024]

// ---- LDS layout (bytes), total 65072 -> 2 blocks/CU ----
constexpr int S_H   = 0;       // f16 h[100][40]   (cols 0..31 used)
constexpr int S_HP  = 8000;    // f16 hp[100][128] (col c -> d=c>>2, h=c&3), XOR-swizzled
constexpr int S_U   = 33600;   // f16 U[100][132]  (4 rels x 32 dims + pad)
constexpr int S_EH  = 60000;   // f32[100][4]
constexpr int S_ET  = 61600;   // f32[100][4]
constexpr int S_DEN = 63200;   // f32[100][4]
constexpr int S_RA  = 64800;   // f32[16][4]
constexpr int S_ESG = 65056;   // f32[4]
constexpr int S_TOTAL = 65072;

typedef _Float16 f16x8 __attribute__((ext_vector_type(8)));
typedef float f32x4 __attribute__((ext_vector_type(4)));

DI float lrelu(float x) { return x >= 0.f ? x : 0.2f * x; }
DI f16x8 u4_to_f16x8(uint4 u) { f16x8 r; __builtin_memcpy(&r, &u, 16); return r; }
DI f16x8 two_u2(uint2 a, uint2 b) { return u4_to_f16x8(make_uint4(a.x, a.y, b.x, b.y)); }

// hp swizzle: half-index for (node n, col c); XOR bits 3..5 with n&7 (16B granularity)
DI int hpIdx(int n, int c) { return n * 128 + (c ^ ((n & 7) << 3)); }

// packed f16 LDS atomic add (ds_pk_add_f16)
DI void ldsPkAddF16(__half* p, float v0, float v1) {
    __half2 hv = __floats2half2_rn(v0, v1);
    unsigned uv; __builtin_memcpy(&uv, &hv, 4);
    unsigned addr = (unsigned)(unsigned long long)p;
    asm volatile("ds_pk_add_f16 %0, %1" :: "v"(addr), "v"(uv) : "memory");
}

// ---------------- binning: (graph, relation) bins, 100 edges/bin ----------------
__global__ void k_zero(int* hist) {
    int i = blockIdx.x * 1024 + threadIdx.x;
    if (i < NBIN) hist[i] = 0;
}

__global__ void k_hist(const int* __restrict__ dst, const int* __restrict__ rt,
                       int* __restrict__ hist) {
    int e = blockIdx.x * 256 + threadIdx.x;
    if (e >= EDGES) return;
    unsigned g = (unsigned)dst[e] / 100u;
    atomicAdd(&hist[g * 16 + rt[e]], 1);
}

__global__ void k_scan(const int* __restrict__ hist, int* __restrict__ off,
                       int* __restrict__ curs) {
    __shared__ int sc[1024];
    int t = threadIdx.x;
    int v[8]; int s = 0;
    #pragma unroll
    for (int i = 0; i < 8; ++i) { int b = t*8 + i; v[i] = (b < NBIN) ? hist[b] : 0; s += v[i]; }
    sc[t] = s; __syncthreads();
    for (int o = 1; o < 1024; o <<= 1) {
        int a = (t >= o) ? sc[t - o] : 0;
        __syncthreads();
        sc[t] += a;
        __syncthreads();
    }
    int run = sc[t] - s;
    #pragma unroll
    for (int i = 0; i < 8; ++i) {
        int b = t*8 + i;
        if (b < NBIN) { off[b] = run; curs[b] = run; }
        run += v[i];
    }
    if (t == 0) off[NBIN] = EDGES;
}

__global__ void k_scatter(const int* __restrict__ src, const int* __restrict__ dst,
                          const int* __restrict__ rt, int* __restrict__ curs,
                          int* __restrict__ meta, int* __restrict__ orig) {
    int e = blockIdx.x * 256 + threadIdx.x;
    if (e >= EDGES) return;
    int s = src[e], d = dst[e], r = rt[e];
    int g = (unsigned)d / 100u;
    int pos = atomicAdd(&curs[g * 16 + r], 1);
    meta[pos] = (s - g * 100) | ((d - g * 100) << 7) | (r << 14);
    orig[pos] = e;
}

// ---------------- setup: prep folds + f16 MFMA fragments ----------------
__global__ void k_setup(const float* __restrict__ rel_table, const float* __restrict__ Wr,
                        const float* __restrict__ br, const float* __restrict__ We,
                        const float* __restrict__ be, const float* __restrict__ attn_r,
                        const float* __restrict__ attn_rs, const float* __restrict__ attn_s,
                        const float* __restrict__ W, float* __restrict__ prep,
                        uint4* __restrict__ wf) {
    __shared__ float wra[2][32][4];
    __shared__ float sbias[2][3][4];
    int b = blockIdx.x, t = threadIdx.x;
    if (b == 0) {
        {
            int l = t >> 7, k = (t >> 2) & 31, h = t & 3;
            float a = 0.f, bb = 0.f, c = 0.f;
            for (int d2 = 0; d2 < 32; ++d2) {
                float w1 = Wr[(size_t)(l*32 + k)*128 + h*32 + d2];
                float w2 = We[(size_t)(l*32 + k)*128 + h*32 + d2];
                a  += w1 * attn_r [l*128 + h*32 + d2];
                bb += w1 * attn_rs[l*128 + h*32 + d2];
                c  += w2 * attn_s [l*128 + h*32 + d2];
            }
            wra[l][k][h] = a;
            prep[128 + (l*32 + k)*4 + h] = bb;
            prep[384 + (l*32 + k)*4 + h] = c;
        }
        if (t < 24) {
            int l = t / 12, which = (t % 12) / 4, h = t % 4;
            const float* bp = (which == 2) ? be : br;
            const float* ap = (which == 0) ? attn_r : (which == 1 ? attn_rs : attn_s);
            float s = 0.f;
            for (int d2 = 0; d2 < 32; ++d2) s += bp[l*128 + h*32 + d2] * ap[l*128 + h*32 + d2];
            sbias[l][which][h] = s;
        }
        __syncthreads();
        if (t < 128) {
            int l = t >> 6, r = (t >> 2) & 15, h = t & 3;
            float s = sbias[l][0][h];
            for (int k = 0; k < 32; ++k) s += rel_table[r*32 + k] * wra[l][k][h];
            prep[(l*16 + r)*4 + h] = s;
        }
        if (t < 8) {
            int l = t >> 2, h = t & 3;
            prep[640 + l*4 + h] = sbias[l][1][h];
            prep[648 + l*4 + h] = sbias[l][2][h];
        }
    } else if (b <= 16) {
        // W fragments (f16): wf[((l*16+rel)*2+Nt)*64 + ln]
        int fi = (b - 1) * 256 + t;
        int ln = fi & 63, Nt = (fi >> 6) & 1, rel = (fi >> 7) & 15, l = fi >> 11;
        int j = Nt*16 + (ln & 15), k0 = (ln >> 4) << 3;
        unsigned short fr[8];
        #pragma unroll
        for (int i = 0; i < 8; ++i) {
            __half hv = __float2half(W[(((size_t)l*16 + rel)*32 + k0 + i)*32 + j]);
            __builtin_memcpy(&fr[i], &hv, 2);
        }
        uint4 o;
        o.x = fr[0] | ((unsigned)fr[1] << 16);
        o.y = fr[2] | ((unsigned)fr[3] << 16);
        o.z = fr[4] | ((unsigned)fr[5] << 16);
        o.w = fr[6] | ((unsigned)fr[7] << 16);
        wf[fi] = o;
    } else {
        // We fragments (f16, column-permuted): col c -> phys (c&3)*32+(c>>2)
        int fi = (b - 17) * 256 + t;
        int ln = fi & 63, Nt = (fi >> 6) & 7, l = fi >> 9;
        int c = Nt*16 + (ln & 15);
        int phys = (c & 3)*32 + (c >> 2);
        int k0 = (ln >> 4) << 3;
        unsigned short fr[8];
        #pragma unroll
        for (int i = 0; i < 8; ++i) {
            __half hv = __float2half(We[(size_t)l*4096 + (k0 + i)*128 + phys]);
            __builtin_memcpy(&fr[i], &hv, 2);
        }
        uint4 o;
        o.x = fr[0] | ((unsigned)fr[1] << 16);
        o.y = fr[2] | ((unsigned)fr[3] << 16);
        o.z = fr[4] | ((unsigned)fr[5] << 16);
        o.w = fr[6] | ((unsigned)fr[7] << 16);
        wf[4096 + fi] = o;
    }
}

// ---------------- fused per-graph forward ----------------
__global__ void __launch_bounds__(512, 2)
k_fused(const float* __restrict__ state, const float* __restrict__ rw,
        const float* __restrict__ code_emb, const float* __restrict__ h_bias,
        const float* __restrict__ be, const float* __restrict__ attn_h,
        const float* __restrict__ attn_t, const int* __restrict__ node_ids,
        const int* __restrict__ off, const int* __restrict__ meta,
        const int* __restrict__ orig, const float* __restrict__ prep,
        const uint4* __restrict__ wf,
        float* __restrict__ xout, float* __restrict__ relOut, float* __restrict__ edgeOut) {
    extern __shared__ char smem[];
    __half* hH  = (__half*)(smem + S_H);
    __half* hpH = (__half*)(smem + S_HP);
    __half* Uh  = (__half*)(smem + S_U);
    float* ehp  = (float*)(smem + S_EH);
    float* etp  = (float*)(smem + S_ET);
    float* denp = (float*)(smem + S_DEN);
    float* rap  = (float*)(smem + S_RA);
    float* esgp = (float*)(smem + S_ESG);
    const uint4* wfe = wf + 4096;

    const int g = blockIdx.x;
    const int t = threadIdx.x;
    const int lane = t & 63, w = t >> 6;
    const int ln15 = lane & 15, q = lane >> 4, q8 = q << 3;
    const int MtA = w % 7, NtA = w / 7;
    const int MtB = (w + 8) % 7, NtB = (w + 8) / 7;
    const bool hasB = (w < 6);
    const int colc = w * 16 + ln15;
    const int physc = (colc & 3) * 32 + (colc >> 2);

    const int gbase = off[g * 16];
    const int ecnt  = off[g * 16 + 16] - gbase;

    // P0: h0 = code_emb[node_ids] (f16, [100][40]); zero eh/et/den
    for (int i = t; i < 1600; i += 512) {
        int n = i >> 4, dp = i & 15;
        int id = node_ids[g * 100 + n];
        float2 v = *(const float2*)&code_emb[(size_t)id * 32 + dp * 2];
        *(__half2*)&hH[n * 40 + dp * 2] = __floats2half2_rn(v.x, v.y);
    }
    for (int i = t; i < 300; i += 512) ((uint4*)(smem + S_EH))[i] = make_uint4(0, 0, 0, 0);

    // edge meta -> registers (4 slots per thread; 2048 >= max edges/graph)
    int em[4];
    #pragma unroll
    for (int k = 0; k < 4; ++k) {
        int e = t + k * 512;
        em[k] = (e < ecnt) ? meta[gbase + e] : -1;
    }

    // scatter pass p: compute final coefficient from LDS state, scatter msg into U
    auto scatterPass = [&](int p, bool writeAtt) {
        float4 esg4 = *(const float4*)esgp;
        #pragma unroll
        for (int k = 0; k < 4; ++k) {
            int m = em[k];
            if (m >= 0 && ((m >> 16) & 3) == p) {
                int s = m & 127, d = (m >> 7) & 127, r = (m >> 14) & 15;
                int cb = (r & 3) * 32;
                int sw = (s & 7) << 3;
                float4 eh4 = *(const float4*)&ehp[s * 4];
                float4 et4 = *(const float4*)&etp[d * 4];
                float4 dn  = *(const float4*)&denp[d * 4];
                float4 r4  = *(const float4*)&rap[r * 4];
                float a0 = __expf(lrelu(eh4.x + et4.x + esg4.x)) / dn.x;
                float a1 = __expf(lrelu(eh4.y + et4.y + esg4.y)) / dn.y;
                float a2 = __expf(lrelu(eh4.z + et4.z + esg4.z)) / dn.z;
                float a3 = __expf(lrelu(eh4.w + et4.w + esg4.w)) / dn.w;
                if (writeAtt) {
                    int oe = orig[gbase + t + k * 512];
                    *(float4*)&edgeOut[(size_t)oe * 4] = make_float4(a0, a1, a2, a3);
                    *(float4*)&relOut[(size_t)oe * 4] = r4;
                }
                float c0 = a0 * r4.x, c1 = a1 * r4.y, c2 = a2 * r4.z, c3 = a3 * r4.w;
                #pragma unroll
                for (int db = 0; db < 16; ++db) {
                    uint4 hv = *(const uint4*)&hpH[s * 128 + ((db * 8) ^ sw)];
                    float2 f01 = __half22float2(*(const __half2*)&hv.x);
                    float2 f23 = __half22float2(*(const __half2*)&hv.y);
                    float2 f45 = __half22float2(*(const __half2*)&hv.z);
                    float2 f67 = __half22float2(*(const __half2*)&hv.w);
                    float v0 = c0*f01.x + c1*f01.y + c2*f23.x + c3*f23.y;
                    float v1 = c0*f45.x + c1*f45.y + c2*f67.x + c3*f67.y;
                    ldsPkAddF16(Uh + d * 132 + cb + db * 2, v0, v1);
                }
            }
        }
    };

    for (int l = 0; l < 2; ++l) {
        __syncthreads();   // B0: h ready, eh/et/den zeroed

        // ---- X1: P2-MFMA (hp = h@We + be) + eh/et epilogue (2-deep pipeline) ----
        {
            uint4 bwe = wfe[(l * 8 + w) * 64 + lane];
            f16x8 bw = u4_to_f16x8(bwe);
            float beC = be[l * 128 + physc];
            float ahC = attn_h[l * 128 + physc];
            float atC = attn_t[l * 128 + physc];
            f32x4 z = {0.f, 0.f, 0.f, 0.f};
            const __half* hr0 = hH + ln15 * 40 + q8;
            f32x4 pcur = __builtin_amdgcn_mfma_f32_16x16x32_f16(
                two_u2(*(const uint2*)hr0, *(const uint2*)(hr0 + 4)), bw, z, 0, 0, 0);
            #pragma unroll
            for (int Mt = 0; Mt < 7; ++Mt) {
                f32x4 pnxt;
                if (Mt < 6) {
                    const __half* hr = hH + ((Mt + 1) * 16 + ln15) * 40 + q8;
                    pnxt = __builtin_amdgcn_mfma_f32_16x16x32_f16(
                        two_u2(*(const uint2*)hr, *(const uint2*)(hr + 4)), bw, z, 0, 0, 0);
                }
                #pragma unroll
                for (int i = 0; i < 4; ++i) {
                    int n = Mt * 16 + q * 4 + i;
                    float hv = pcur[i] + beC;
                    bool ok = (n < 100);
                    if (ok) hpH[hpIdx(n, colc)] = __float2half(hv);
                    float veh = ok ? hv * ahC : 0.f;
                    float vet = ok ? hv * atC : 0.f;
                    veh += __shfl_xor(veh, 4); vet += __shfl_xor(vet, 4);
                    veh += __shfl_xor(veh, 8); vet += __shfl_xor(vet, 8);
                    if (ok && (ln15 & 12) == 0) {
                        atomicAdd(&ehp[n * 4 + (ln15 & 3)], veh);
                        atomicAdd(&etp[n * 4 + (ln15 & 3)], vet);
                    }
                }
                pcur = pnxt;
            }
        }
        {   // P1: relation attention (all waves redundantly)
            int k32 = lane & 31;
            float sG = state[g * 32 + k32];
            float4 frs = *(const float4*)&prep[128 + l * 128 + k32 * 4];
            float4 fes = *(const float4*)&prep[384 + l * 128 + k32 * 4];
            float p0 = sG * frs.x, p1 = sG * frs.y, p2 = sG * frs.z, p3 = sG * frs.w;
            float q0 = sG * fes.x, q1 = sG * fes.y, q2 = sG * fes.z, q3 = sG * fes.w;
            #pragma unroll
            for (int m = 1; m < 32; m <<= 1) {
                p0 += __shfl_xor(p0, m); p1 += __shfl_xor(p1, m);
                p2 += __shfl_xor(p2, m); p3 += __shfl_xor(p3, m);
                q0 += __shfl_xor(q0, m); q1 += __shfl_xor(q1, m);
                q2 += __shfl_xor(q2, m); q3 += __shfl_xor(q3, m);
            }
            int h = lane & 3;
            float esh  = (h & 2) ? ((h & 1) ? p3 : p2) : ((h & 1) ? p1 : p0);
            float esgh = (h & 2) ? ((h & 1) ? q3 : q2) : ((h & 1) ? q1 : q0);
            esh  += prep[640 + l * 4 + h];
            esgh += prep[648 + l * 4 + h];
            if (lane < 4) esgp[lane] = esgh;
            float er = prep[l * 64 + lane];
            float ex = __expf(lrelu(er + esh));
            float s = ex;
            s += __shfl_xor(s, 4); s += __shfl_xor(s, 8);
            s += __shfl_xor(s, 16); s += __shfl_xor(s, 32);
            rap[lane] = ex / s;
        }
        __syncthreads();   // B1: hp/eh/et/rap/esg ready

        // ---- X2: zero U; edge exp -> den ----
        for (int i = t; i < 1650; i += 512) ((uint4*)(smem + S_U))[i] = make_uint4(0, 0, 0, 0);
        {
            float4 esg4 = *(const float4*)esgp;
            #pragma unroll
            for (int k = 0; k < 4; ++k) {
                int m = em[k];
                if (m >= 0) {
                    int s = m & 127, d = (m >> 7) & 127;
                    float4 eh4 = *(const float4*)&ehp[s * 4];
                    float4 et4 = *(const float4*)&etp[d * 4];
                    atomicAdd(&denp[d * 4 + 0], __expf(lrelu(eh4.x + et4.x + esg4.x)));
                    atomicAdd(&denp[d * 4 + 1], __expf(lrelu(eh4.y + et4.y + esg4.y)));
                    atomicAdd(&denp[d * 4 + 2], __expf(lrelu(eh4.z + et4.z + esg4.z)));
                    atomicAdd(&denp[d * 4 + 3], __expf(lrelu(eh4.w + et4.w + esg4.w)));
                }
            }
        }
        __syncthreads();   // B2: den final, U zeroed

        scatterPass(0, l == 1);
        __syncthreads();   // B3: U(0) scattered

        // ---- P7: 4 passes of MFMA over relation quads (B-frags loaded just-in-time) ----
        f32x4 accA = {0.f, 0.f, 0.f, 0.f};
        f32x4 accB = {0.f, 0.f, 0.f, 0.f};
        for (int p = 0; p < 4; ++p) {
            #pragma unroll
            for (int kq = 0; kq < 4; ++kq) {
                int rel = p * 4 + kq;
                {
                    uint4 bAu = wf[((l * 16 + rel) * 2 + NtA) * 64 + lane];
                    const __half* up = Uh + (MtA * 16 + ln15) * 132 + kq * 32 + q8;
                    f16x8 af = two_u2(*(const uint2*)up, *(const uint2*)(up + 4));
                    accA = __builtin_amdgcn_mfma_f32_16x16x32_f16(af, u4_to_f16x8(bAu), accA, 0, 0, 0);
                }
                if (hasB) {
                    uint4 bBu = wf[((l * 16 + rel) * 2 + NtB) * 64 + lane];
                    const __half* up = Uh + (MtB * 16 + ln15) * 132 + kq * 32 + q8;
                    f16x8 af = two_u2(*(const uint2*)up, *(const uint2*)(up + 4));
                    accB = __builtin_amdgcn_mfma_f32_16x16x32_f16(af, u4_to_f16x8(bBu), accB, 0, 0, 0);
                }
            }
            if (p < 3) {
                __syncthreads();   // U consumed by all waves
                for (int i = t; i < 1650; i += 512) ((uint4*)(smem + S_U))[i] = make_uint4(0, 0, 0, 0);
                __syncthreads();   // U zeroed
                scatterPass(p + 1, l == 1);
                __syncthreads();   // scattered
            } else {
                // P8: h = relu(0.5*(agg+bias) + 0.5*h); zero eh/et/den for next layer
                if (l == 0)
                    for (int i = t; i < 300; i += 512) ((uint4*)(smem + S_EH))[i] = make_uint4(0, 0, 0, 0);
                {
                    int dcol = NtA * 16 + ln15;
                    float bias = h_bias[l * 32 + dcol];
                    #pragma unroll
                    for (int i = 0; i < 4; ++i) {
                        int n = MtA * 16 + q * 4 + i;
                        if (n < 100) {
                            float hold = __half2float(hH[n * 40 + dcol]);
                            float hn = fmaxf(0.f, 0.5f * (accA[i] + bias) + 0.5f * hold);
                            hH[n * 40 + dcol] = __float2half(hn);
                        }
                    }
                }
                if (hasB) {
                    int dcol = NtB * 16 + ln15;
                    float bias = h_bias[l * 32 + dcol];
                    #pragma unroll
                    for (int i = 0; i < 4; ++i) {
                        int n = MtB * 16 + q * 4 + i;
                        if (n < 100) {
                            float hold = __half2float(hH[n * 40 + dcol]);
                            float hn = fmaxf(0.f, 0.5f * (accB[i] + bias) + 0.5f * hold);
                            hH[n * 40 + dcol] = __float2half(hn);
                        }
                    }
                }
            }
        }
    }
    __syncthreads();   // h final

    // P9: readout x[g] = sum_n h[n] * rw[n]   (red buffer reuses U region)
    float* redp = (float*)(smem + S_U);
    {
        int part = t >> 5, d = t & 31;
        float acc = 0.f;
        for (int n = part; n < 100; n += 16)
            acc += __half2float(hH[n * 40 + d]) * rw[g * 100 + n];
        redp[part * 32 + d] = acc;
    }
    __syncthreads();
    if (t < 32) {
        float s = 0.f;
        #pragma unroll
        for (int p = 0; p < 16; ++p) s += redp[p * 32 + t];
        xout[g * 32 + t] = s;
    }
}

extern "C" void kernel_launch(void* const* d_in, const int* in_sizes, int n_in,
                              void* d_out, int out_size, void* d_ws, size_t ws_size,
                              hipStream_t stream) {
    const float* state     = (const float*)d_in[0];
    const float* rw        = (const float*)d_in[1];
    const float* code_emb  = (const float*)d_in[2];
    const float* rel_table = (const float*)d_in[3];
    const float* W         = (const float*)d_in[4];
    const float* h_bias    = (const float*)d_in[5];
    const float* Wr        = (const float*)d_in[6];
    const float* br        = (const float*)d_in[7];
    const float* We        = (const float*)d_in[8];
    const float* be        = (const float*)d_in[9];
    const float* attn_h    = (const float*)d_in[10];
    const float* attn_t    = (const float*)d_in[11];
    const float* attn_s    = (const float*)d_in[12];
    const float* attn_r    = (const float*)d_in[13];
    const float* attn_rs   = (const float*)d_in[14];
    const int* node_ids    = (const int*)d_in[15];
    const int* src         = (const int*)d_in[16];
    const int* dst         = (const int*)d_in[17];
    const int* rtype       = (const int*)d_in[18];

    float* out = (float*)d_out;
    float* xout = out;
    float* relOut = out + (size_t)NGRAPH * 32;
    float* edgeOut = relOut + (size_t)EDGES * 4;

    int* wsi = (int*)d_ws;
    float* wsf = (float*)d_ws;
    int* hist = wsi + WI_HIST;
    int* off  = wsi + WI_OFF;
    int* curs = wsi + WI_CURS;
    int* meta = wsi + WI_META;
    int* orig = wsi + WI_ORIG;
    float* prep = wsf + WF_PREP;
    uint4* wfrag = (uint4*)(wsf + WF_WFRAG);

    k_zero<<<(NBIN + 1023) / 1024, 1024, 0, stream>>>(hist);
    k_hist<<<(EDGES + 255) / 256, 256, 0, stream>>>(dst, rtype, hist);
    k_scan<<<1, 1024, 0, stream>>>(hist, off, curs);
    k_scatter<<<(EDGES + 255) / 256, 256, 0, stream>>>(src, dst, rtype, curs, meta, orig);
    k_setup<<<21, 256, 0, stream>>>(rel_table, Wr, br, We, be, attn_r, attn_rs, attn_s,
                                    W, prep, wfrag);

    (void)hipFuncSetAttribute((const void*)k_fused, hipFuncAttributeMaxDynamicSharedMemorySize, S_TOTAL);
    k_fused<<<NGRAPH, 512, S_TOTAL, stream>>>(state, rw, code_emb, h_bias, be,
                                              attn_h, attn_t, node_ids, off, meta, orig,
                                              prep, wfrag, xout, relOut, edgeOut);
}

// Round 10
// 358.202 us; speedup vs baseline: 2.6771x; 1.0222x over previous
//
#include <hip/hip_runtime.h>
#include <hip/hip_fp16.h>

#define DI __device__ __forceinline__

constexpr int NGRAPH = 500;
constexpr int EDGES  = 800000;
constexpr int NBIN   = NGRAPH * 16;   // (graph, relation)

// ---- workspace layout (4-byte units) ----
constexpr size_t WI_HIST = 0;                    // [8000]
constexpr size_t WI_OFF  = WI_HIST + NBIN;       // [8001]
constexpr size_t WI_CURS = WI_OFF + NBIN + 1;    // [8000]
constexpr size_t WI_META = WI_CURS + NBIN;       // [E]
constexpr size_t WI_ORIG = WI_META + EDGES;      // [E]
constexpr size_t WF_PREP = WI_ORIG + EDGES;      // 656 floats
constexpr size_t WF_WFRAG = WF_PREP + 672;       // uint4[5120]: W-frags[4096] + We-frags[1024]

// ---- LDS layout (bytes), total 65072 -> 2 blocks/CU ----
constexpr int S_H   = 0;       // f16 h[100][40]   (cols 0..31 used)
constexpr int S_HP  = 8000;    // f16 hp[100][128] (col c -> d=c>>2, h=c&3), XOR-swizzled
constexpr int S_U   = 33600;   // f16 U[100][132]  (4 rels x 32 dims + pad)
constexpr int S_EH  = 60000;   // f32[100][4]
constexpr int S_ET  = 61600;   // f32[100][4]
constexpr int S_DEN = 63200;   // f32[100][4]
constexpr int S_RA  = 64800;   // f32[16][4]
constexpr int S_ESG = 65056;   // f32[4]
constexpr int S_TOTAL = 65072;

typedef _Float16 f16x8 __attribute__((ext_vector_type(8)));
typedef float f32x4 __attribute__((ext_vector_type(4)));

DI float lrelu(float x) { return x >= 0.f ? x : 0.2f * x; }
DI f16x8 u4_to_f16x8(uint4 u) { f16x8 r; __builtin_memcpy(&r, &u, 16); return r; }
DI f16x8 two_u2(uint2 a, uint2 b) { return u4_to_f16x8(make_uint4(a.x, a.y, b.x, b.y)); }

// hp swizzle: half-index for (node n, col c); XOR bits 3..5 with n&7 (16B granularity)
DI int hpIdx(int n, int c) { return n * 128 + (c ^ ((n & 7) << 3)); }

// packed f16 LDS atomic add (ds_pk_add_f16)
DI void ldsPkAddF16(__half* p, float v0, float v1) {
    __half2 hv = __floats2half2_rn(v0, v1);
    unsigned uv; __builtin_memcpy(&uv, &hv, 4);
    unsigned addr = (unsigned)(unsigned long long)p;
    asm volatile("ds_pk_add_f16 %0, %1" :: "v"(addr), "v"(uv) : "memory");
}

// ---------------- binning: (graph, relation) bins, 100 edges/bin ----------------
__global__ void k_hist(const int* __restrict__ dst, const int* __restrict__ rt,
                       int* __restrict__ hist) {
    int e = blockIdx.x * 256 + threadIdx.x;
    if (e >= EDGES) return;
    unsigned g = (unsigned)dst[e] / 100u;
    atomicAdd(&hist[g * 16 + rt[e]], 1);
}

__global__ void k_scan(const int* __restrict__ hist, int* __restrict__ off,
                       int* __restrict__ curs) {
    __shared__ int sc[1024];
    int t = threadIdx.x;
    int v[8]; int s = 0;
    #pragma unroll
    for (int i = 0; i < 8; ++i) { int b = t*8 + i; v[i] = (b < NBIN) ? hist[b] : 0; s += v[i]; }
    sc[t] = s; __syncthreads();
    for (int o = 1; o < 1024; o <<= 1) {
        int a = (t >= o) ? sc[t - o] : 0;
        __syncthreads();
        sc[t] += a;
        __syncthreads();
    }
    int run = sc[t] - s;
    #pragma unroll
    for (int i = 0; i < 8; ++i) {
        int b = t*8 + i;
        if (b < NBIN) { off[b] = run; curs[b] = run; }
        run += v[i];
    }
    if (t == 0) off[NBIN] = EDGES;
}

__global__ void k_scatter(const int* __restrict__ src, const int* __restrict__ dst,
                          const int* __restrict__ rt, int* __restrict__ curs,
                          int* __restrict__ meta, int* __restrict__ orig) {
    int e = blockIdx.x * 256 + threadIdx.x;
    if (e >= EDGES) return;
    int s = src[e], d = dst[e], r = rt[e];
    int g = (unsigned)d / 100u;
    int pos = atomicAdd(&curs[g * 16 + r], 1);
    meta[pos] = (s - g * 100) | ((d - g * 100) << 7) | (r << 14);
    orig[pos] = e;
}

// ---------------- setup: prep folds + f16 MFMA fragments ----------------
__global__ void k_setup(const float* __restrict__ rel_table, const float* __restrict__ Wr,
                        const float* __restrict__ br, const float* __restrict__ We,
                        const float* __restrict__ be, const float* __restrict__ attn_r,
                        const float* __restrict__ attn_rs, const float* __restrict__ attn_s,
                        const float* __restrict__ W, float* __restrict__ prep,
                        uint4* __restrict__ wf) {
    __shared__ float wra[2][32][4];
    __shared__ float sbias[2][3][4];
    int b = blockIdx.x, t = threadIdx.x;
    if (b == 0) {
        {
            int l = t >> 7, k = (t >> 2) & 31, h = t & 3;
            float a = 0.f, bb = 0.f, c = 0.f;
            for (int d2 = 0; d2 < 32; ++d2) {
                float w1 = Wr[(size_t)(l*32 + k)*128 + h*32 + d2];
                float w2 = We[(size_t)(l*32 + k)*128 + h*32 + d2];
                a  += w1 * attn_r [l*128 + h*32 + d2];
                bb += w1 * attn_rs[l*128 + h*32 + d2];
                c  += w2 * attn_s [l*128 + h*32 + d2];
            }
            wra[l][k][h] = a;
            prep[128 + (l*32 + k)*4 + h] = bb;
            prep[384 + (l*32 + k)*4 + h] = c;
        }
        if (t < 24) {
            int l = t / 12, which = (t % 12) / 4, h = t % 4;
            const float* bp = (which == 2) ? be : br;
            const float* ap = (which == 0) ? attn_r : (which == 1 ? attn_rs : attn_s);
            float s = 0.f;
            for (int d2 = 0; d2 < 32; ++d2) s += bp[l*128 + h*32 + d2] * ap[l*128 + h*32 + d2];
            sbias[l][which][h] = s;
        }
        __syncthreads();
        if (t < 128) {
            int l = t >> 6, r = (t >> 2) & 15, h = t & 3;
            float s = sbias[l][0][h];
            for (int k = 0; k < 32; ++k) s += rel_table[r*32 + k] * wra[l][k][h];
            prep[(l*16 + r)*4 + h] = s;
        }
        if (t < 8) {
            int l = t >> 2, h = t & 3;
            prep[640 + l*4 + h] = sbias[l][1][h];
            prep[648 + l*4 + h] = sbias[l][2][h];
        }
    } else if (b <= 16) {
        // W fragments (f16): wf[((l*16+rel)*2+Nt)*64 + ln]
        int fi = (b - 1) * 256 + t;
        int ln = fi & 63, Nt = (fi >> 6) & 1, rel = (fi >> 7) & 15, l = fi >> 11;
        int j = Nt*16 + (ln & 15), k0 = (ln >> 4) << 3;
        unsigned short fr[8];
        #pragma unroll
        for (int i = 0; i < 8; ++i) {
            __half hv = __float2half(W[(((size_t)l*16 + rel)*32 + k0 + i)*32 + j]);
            __builtin_memcpy(&fr[i], &hv, 2);
        }
        uint4 o;
        o.x = fr[0] | ((unsigned)fr[1] << 16);
        o.y = fr[2] | ((unsigned)fr[3] << 16);
        o.z = fr[4] | ((unsigned)fr[5] << 16);
        o.w = fr[6] | ((unsigned)fr[7] << 16);
        wf[fi] = o;
    } else {
        // We fragments (f16, column-permuted): col c -> phys (c&3)*32+(c>>2)
        int fi = (b - 17) * 256 + t;
        int ln = fi & 63, Nt = (fi >> 6) & 7, l = fi >> 9;
        int c = Nt*16 + (ln & 15);
        int phys = (c & 3)*32 + (c >> 2);
        int k0 = (ln >> 4) << 3;
        unsigned short fr[8];
        #pragma unroll
        for (int i = 0; i < 8; ++i) {
            __half hv = __float2half(We[(size_t)l*4096 + (k0 + i)*128 + phys]);
            __builtin_memcpy(&fr[i], &hv, 2);
        }
        uint4 o;
        o.x = fr[0] | ((unsigned)fr[1] << 16);
        o.y = fr[2] | ((unsigned)fr[3] << 16);
        o.z = fr[4] | ((unsigned)fr[5] << 16);
        o.w = fr[6] | ((unsigned)fr[7] << 16);
        wf[4096 + fi] = o;
    }
}

// ---------------- fused per-graph forward ----------------
__global__ void __launch_bounds__(512, 4)
k_fused(const float* __restrict__ state, const float* __restrict__ rw,
        const float* __restrict__ code_emb, const float* __restrict__ h_bias,
        const float* __restrict__ be, const float* __restrict__ attn_h,
        const float* __restrict__ attn_t, const int* __restrict__ node_ids,
        const int* __restrict__ off, const int* __restrict__ meta,
        const int* __restrict__ orig, const float* __restrict__ prep,
        const uint4* __restrict__ wf,
        float* __restrict__ xout, float* __restrict__ relOut, float* __restrict__ edgeOut) {
    extern __shared__ char smem[];
    __half* hH  = (__half*)(smem + S_H);
    __half* hpH = (__half*)(smem + S_HP);
    __half* Uh  = (__half*)(smem + S_U);
    float* ehp  = (float*)(smem + S_EH);
    float* etp  = (float*)(smem + S_ET);
    float* denp = (float*)(smem + S_DEN);
    float* rap  = (float*)(smem + S_RA);
    float* esgp = (float*)(smem + S_ESG);
    const uint4* wfe = wf + 4096;

    const int g = blockIdx.x;
    const int t = threadIdx.x;
    const int lane = t & 63, w = t >> 6;
    const int ln15 = lane & 15, q = lane >> 4, q8 = q << 3;
    const int MtA = w % 7, NtA = w / 7;
    const int MtB = (w + 8) % 7, NtB = (w + 8) / 7;
    const bool hasB = (w < 6);
    const int colc = w * 16 + ln15;
    const int physc = (colc & 3) * 32 + (colc >> 2);

    const int gbase = off[g * 16];
    const int ecnt  = off[g * 16 + 16] - gbase;

    // P0: h0 = code_emb[node_ids] (f16, [100][40]); zero eh/et/den
    for (int i = t; i < 1600; i += 512) {
        int n = i >> 4, dp = i & 15;
        int id = node_ids[g * 100 + n];
        float2 v = *(const float2*)&code_emb[(size_t)id * 32 + dp * 2];
        *(__half2*)&hH[n * 40 + dp * 2] = __floats2half2_rn(v.x, v.y);
    }
    for (int i = t; i < 300; i += 512) ((uint4*)(smem + S_EH))[i] = make_uint4(0, 0, 0, 0);

    // edge meta -> registers (4 slots per thread; 2048 >= max edges/graph)
    int em[4];
    #pragma unroll
    for (int k = 0; k < 4; ++k) {
        int e = t + k * 512;
        em[k] = (e < ecnt) ? meta[gbase + e] : -1;
    }

    // scatter pass p: compute final coefficient from LDS state, scatter msg into U
    auto scatterPass = [&](int p, bool writeAtt) {
        float4 esg4 = *(const float4*)esgp;
        #pragma unroll
        for (int k = 0; k < 4; ++k) {
            int m = em[k];
            if (m >= 0 && ((m >> 16) & 3) == p) {
                int s = m & 127, d = (m >> 7) & 127, r = (m >> 14) & 15;
                int cb = (r & 3) * 32;
                int sw = (s & 7) << 3;
                float4 eh4 = *(const float4*)&ehp[s * 4];
                float4 et4 = *(const float4*)&etp[d * 4];
                float4 dn  = *(const float4*)&denp[d * 4];
                float4 r4  = *(const float4*)&rap[r * 4];
                float a0 = __expf(lrelu(eh4.x + et4.x + esg4.x)) / dn.x;
                float a1 = __expf(lrelu(eh4.y + et4.y + esg4.y)) / dn.y;
                float a2 = __expf(lrelu(eh4.z + et4.z + esg4.z)) / dn.z;
                float a3 = __expf(lrelu(eh4.w + et4.w + esg4.w)) / dn.w;
                if (writeAtt) {
                    int oe = orig[gbase + t + k * 512];
                    *(float4*)&edgeOut[(size_t)oe * 4] = make_float4(a0, a1, a2, a3);
                    *(float4*)&relOut[(size_t)oe * 4] = r4;
                }
                float c0 = a0 * r4.x, c1 = a1 * r4.y, c2 = a2 * r4.z, c3 = a3 * r4.w;
                #pragma unroll 4
                for (int db = 0; db < 16; ++db) {
                    uint4 hv = *(const uint4*)&hpH[s * 128 + ((db * 8) ^ sw)];
                    float2 f01 = __half22float2(*(const __half2*)&hv.x);
                    float2 f23 = __half22float2(*(const __half2*)&hv.y);
                    float2 f45 = __half22float2(*(const __half2*)&hv.z);
                    float2 f67 = __half22float2(*(const __half2*)&hv.w);
                    float v0 = c0*f01.x + c1*f01.y + c2*f23.x + c3*f23.y;
                    float v1 = c0*f45.x + c1*f45.y + c2*f67.x + c3*f67.y;
                    ldsPkAddF16(Uh + d * 132 + cb + db * 2, v0, v1);
                }
            }
        }
    };

    for (int l = 0; l < 2; ++l) {
        __syncthreads();   // B0: h ready, eh/et/den zeroed

        // ---- X1: P2-MFMA (hp = h@We + be) + eh/et epilogue (2-deep pipeline) ----
        {
            uint4 bwe = wfe[(l * 8 + w) * 64 + lane];
            f16x8 bw = u4_to_f16x8(bwe);
            float beC = be[l * 128 + physc];
            float ahC = attn_h[l * 128 + physc];
            float atC = attn_t[l * 128 + physc];
            f32x4 z = {0.f, 0.f, 0.f, 0.f};
            const __half* hr0 = hH + ln15 * 40 + q8;
            f32x4 pcur = __builtin_amdgcn_mfma_f32_16x16x32_f16(
                two_u2(*(const uint2*)hr0, *(const uint2*)(hr0 + 4)), bw, z, 0, 0, 0);
            #pragma unroll
            for (int Mt = 0; Mt < 7; ++Mt) {
                f32x4 pnxt;
                if (Mt < 6) {
                    const __half* hr = hH + ((Mt + 1) * 16 + ln15) * 40 + q8;
                    pnxt = __builtin_amdgcn_mfma_f32_16x16x32_f16(
                        two_u2(*(const uint2*)hr, *(const uint2*)(hr + 4)), bw, z, 0, 0, 0);
                }
                #pragma unroll
                for (int i = 0; i < 4; ++i) {
                    int n = Mt * 16 + q * 4 + i;
                    float hv = pcur[i] + beC;
                    bool ok = (n < 100);
                    if (ok) hpH[hpIdx(n, colc)] = __float2half(hv);
                    float veh = ok ? hv * ahC : 0.f;
                    float vet = ok ? hv * atC : 0.f;
                    veh += __shfl_xor(veh, 4); vet += __shfl_xor(vet, 4);
                    veh += __shfl_xor(veh, 8); vet += __shfl_xor(vet, 8);
                    if (ok && (ln15 & 12) == 0) {
                        atomicAdd(&ehp[n * 4 + (ln15 & 3)], veh);
                        atomicAdd(&etp[n * 4 + (ln15 & 3)], vet);
                    }
                }
                pcur = pnxt;
            }
        }
        {   // P1: relation attention (all waves redundantly)
            int k32 = lane & 31;
            float sG = state[g * 32 + k32];
            float4 frs = *(const float4*)&prep[128 + l * 128 + k32 * 4];
            float4 fes = *(const float4*)&prep[384 + l * 128 + k32 * 4];
            float p0 = sG * frs.x, p1 = sG * frs.y, p2 = sG * frs.z, p3 = sG * frs.w;
            float q0 = sG * fes.x, q1 = sG * fes.y, q2 = sG * fes.z, q3 = sG * fes.w;
            #pragma unroll
            for (int m = 1; m < 32; m <<= 1) {
                p0 += __shfl_xor(p0, m); p1 += __shfl_xor(p1, m);
                p2 += __shfl_xor(p2, m); p3 += __shfl_xor(p3, m);
                q0 += __shfl_xor(q0, m); q1 += __shfl_xor(q1, m);
                q2 += __shfl_xor(q2, m); q3 += __shfl_xor(q3, m);
            }
            int h = lane & 3;
            float esh  = (h & 2) ? ((h & 1) ? p3 : p2) : ((h & 1) ? p1 : p0);
            float esgh = (h & 2) ? ((h & 1) ? q3 : q2) : ((h & 1) ? q1 : q0);
            esh  += prep[640 + l * 4 + h];
            esgh += prep[648 + l * 4 + h];
            if (lane < 4) esgp[lane] = esgh;
            float er = prep[l * 64 + lane];
            float ex = __expf(lrelu(er + esh));
            float s = ex;
            s += __shfl_xor(s, 4); s += __shfl_xor(s, 8);
            s += __shfl_xor(s, 16); s += __shfl_xor(s, 32);
            rap[lane] = ex / s;
        }
        __syncthreads();   // B1: hp/eh/et/rap/esg ready

        // ---- X2: zero U; edge exp -> den ----
        for (int i = t; i < 1650; i += 512) ((uint4*)(smem + S_U))[i] = make_uint4(0, 0, 0, 0);
        {
            float4 esg4 = *(const float4*)esgp;
            #pragma unroll
            for (int k = 0; k < 4; ++k) {
                int m = em[k];
                if (m >= 0) {
                    int s = m & 127, d = (m >> 7) & 127;
                    float4 eh4 = *(const float4*)&ehp[s * 4];
                    float4 et4 = *(const float4*)&etp[d * 4];
                    atomicAdd(&denp[d * 4 + 0], __expf(lrelu(eh4.x + et4.x + esg4.x)));
                    atomicAdd(&denp[d * 4 + 1], __expf(lrelu(eh4.y + et4.y + esg4.y)));
                    atomicAdd(&denp[d * 4 + 2], __expf(lrelu(eh4.z + et4.z + esg4.z)));
                    atomicAdd(&denp[d * 4 + 3], __expf(lrelu(eh4.w + et4.w + esg4.w)));
                }
            }
        }
        __syncthreads();   // B2: den final, U zeroed

        scatterPass(0, l == 1);
        __syncthreads();   // B3: U(0) scattered

        // ---- P7: 4 passes of MFMA over relation quads (B-frags loaded just-in-time) ----
        f32x4 accA = {0.f, 0.f, 0.f, 0.f};
        f32x4 accB = {0.f, 0.f, 0.f, 0.f};
        for (int p = 0; p < 4; ++p) {
            #pragma unroll 2
            for (int kq = 0; kq < 4; ++kq) {
                int rel = p * 4 + kq;
                {
                    uint4 bAu = wf[((l * 16 + rel) * 2 + NtA) * 64 + lane];
                    const __half* up = Uh + (MtA * 16 + ln15) * 132 + kq * 32 + q8;
                    f16x8 af = two_u2(*(const uint2*)up, *(const uint2*)(up + 4));
                    accA = __builtin_amdgcn_mfma_f32_16x16x32_f16(af, u4_to_f16x8(bAu), accA, 0, 0, 0);
                }
                if (hasB) {
                    uint4 bBu = wf[((l * 16 + rel) * 2 + NtB) * 64 + lane];
                    const __half* up = Uh + (MtB * 16 + ln15) * 132 + kq * 32 + q8;
                    f16x8 af = two_u2(*(const uint2*)up, *(const uint2*)(up + 4));
                    accB = __builtin_amdgcn_mfma_f32_16x16x32_f16(af, u4_to_f16x8(bBu), accB, 0, 0, 0);
                }
            }
            if (p < 3) {
                __syncthreads();   // U consumed by all waves
                for (int i = t; i < 1650; i += 512) ((uint4*)(smem + S_U))[i] = make_uint4(0, 0, 0, 0);
                __syncthreads();   // U zeroed
                scatterPass(p + 1, l == 1);
                __syncthreads();   // scattered
            } else {
                // P8: h = relu(0.5*(agg+bias) + 0.5*h); zero eh/et/den for next layer
                if (l == 0)
                    for (int i = t; i < 300; i += 512) ((uint4*)(smem + S_EH))[i] = make_uint4(0, 0, 0, 0);
                {
                    int dcol = NtA * 16 + ln15;
                    float bias = h_bias[l * 32 + dcol];
                    #pragma unroll
                    for (int i = 0; i < 4; ++i) {
                        int n = MtA * 16 + q * 4 + i;
                        if (n < 100) {
                            float hold = __half2float(hH[n * 40 + dcol]);
                            float hn = fmaxf(0.f, 0.5f * (accA[i] + bias) + 0.5f * hold);
                            hH[n * 40 + dcol] = __float2half(hn);
                        }
                    }
                }
                if (hasB) {
                    int dcol = NtB * 16 + ln15;
                    float bias = h_bias[l * 32 + dcol];
                    #pragma unroll
                    for (int i = 0; i < 4; ++i) {
                        int n = MtB * 16 + q * 4 + i;
                        if (n < 100) {
                            float hold = __half2float(hH[n * 40 + dcol]);
                            float hn = fmaxf(0.f, 0.5f * (accB[i] + bias) + 0.5f * hold);
                            hH[n * 40 + dcol] = __float2half(hn);
                        }
                    }
                }
            }
        }
    }
    __syncthreads();   // h final

    // P9: readout x[g] = sum_n h[n] * rw[n]   (red buffer reuses U region)
    float* redp = (float*)(smem + S_U);
    {
        int part = t >> 5, d = t & 31;
        float acc = 0.f;
        for (int n = part; n < 100; n += 16)
            acc += __half2float(hH[n * 40 + d]) * rw[g * 100 + n];
        redp[part * 32 + d] = acc;
    }
    __syncthreads();
    if (t < 32) {
        float s = 0.f;
        #pragma unroll
        for (int p = 0; p < 16; ++p) s += redp[p * 32 + t];
        xout[g * 32 + t] = s;
    }
}

extern "C" void kernel_launch(void* const* d_in, const int* in_sizes, int n_in,
                              void* d_out, int out_size, void* d_ws, size_t ws_size,
                              hipStream_t stream) {
    const float* state     = (const float*)d_in[0];
    const float* rw        = (const float*)d_in[1];
    const float* code_emb  = (const float*)d_in[2];
    const float* rel_table = (const float*)d_in[3];
    const float* W         = (const float*)d_in[4];
    const float* h_bias    = (const float*)d_in[5];
    const float* Wr        = (const float*)d_in[6];
    const float* br        = (const float*)d_in[7];
    const float* We        = (const float*)d_in[8];
    const float* be        = (const float*)d_in[9];
    const float* attn_h    = (const float*)d_in[10];
    const float* attn_t    = (const float*)d_in[11];
    const float* attn_s    = (const float*)d_in[12];
    const float* attn_r    = (const float*)d_in[13];
    const float* attn_rs   = (const float*)d_in[14];
    const int* node_ids    = (const int*)d_in[15];
    const int* src         = (const int*)d_in[16];
    const int* dst         = (const int*)d_in[17];
    const int* rtype       = (const int*)d_in[18];

    float* out = (float*)d_out;
    float* xout = out;
    float* relOut = out + (size_t)NGRAPH * 32;
    float* edgeOut = relOut + (size_t)EDGES * 4;

    int* wsi = (int*)d_ws;
    float* wsf = (float*)d_ws;
    int* hist = wsi + WI_HIST;
    int* off  = wsi + WI_OFF;
    int* curs = wsi + WI_CURS;
    int* meta = wsi + WI_META;
    int* orig = wsi + WI_ORIG;
    float* prep = wsf + WF_PREP;
    uint4* wfrag = (uint4*)(wsf + WF_WFRAG);

    (void)hipMemsetAsync(hist, 0, NBIN * sizeof(int), stream);
    k_hist<<<(EDGES + 255) / 256, 256, 0, stream>>>(dst, rtype, hist);
    k_scan<<<1, 1024, 0, stream>>>(hist, off, curs);
    k_scatter<<<(EDGES + 255) / 256, 256, 0, stream>>>(src, dst, rtype, curs, meta, orig);
    k_setup<<<21, 256, 0, stream>>>(rel_table, Wr, br, We, be, attn_r, attn_rs, attn_s,
                                    W, prep, wfrag);

    (void)hipFuncSetAttribute((const void*)k_fused, hipFuncAttributeMaxDynamicSharedMemorySize, S_TOTAL);
    k_fused<<<NGRAPH, 512, S_TOTAL, stream>>>(state, rw, code_emb, h_bias, be,
                                              attn_h, attn_t, node_ids, off, meta, orig,
                                              prep, wfrag, xout, relOut, edgeOut);
}